// Round 13
// baseline (770.337 us; speedup 1.0000x reference)
//
#include <hip/hip_runtime.h>

// Problem constants
constexpr int B  = 2;
constexpr int N  = 2048;
constexpr int H  = 16;
constexpr int C  = 256;
constexpr int J  = C + 1 + N;    // 2305
constexpr int Jp = 2368;         // J padded to multiple of 64
constexpr int NT = Jp / 64;      // 37 j-tiles
constexpr float EPS = 1e-5f;
constexpr float LOG2E = 1.4426950408889634f;

typedef __bf16 bf16x8 __attribute__((ext_vector_type(8)));
typedef float  f32x4  __attribute__((ext_vector_type(4)));
typedef unsigned int uint4v __attribute__((ext_vector_type(4)));
typedef __attribute__((address_space(3))) unsigned int lds_u32;
typedef const __attribute__((address_space(1))) unsigned int glb_u32;

__device__ inline void load_lds16(const void* g, void* l) {
    __builtin_amdgcn_global_load_lds((glb_u32*)g, (lds_u32*)l, 16, 0, 0);
}
__device__ inline unsigned short f2bf(float f) {
    unsigned int u = __builtin_bit_cast(unsigned int, f);
    u += 0x7fffu + ((u >> 16) & 1u);
    return (unsigned short)(u >> 16);
}
__device__ inline unsigned int packbf2(float a, float b) {
    union { __bf16 h[2]; unsigned int u; } cv;
    cv.h[0] = (__bf16)a;
    cv.h[1] = (__bf16)b;
    return cv.u;
}
__device__ inline float fexp2(float x) {
    float r;
    asm("v_exp_f32 %0, %1" : "=v"(r) : "v"(x));
    return r;
}
__device__ inline f32x4 mfma16(bf16x8 a, bf16x8 b, f32x4 c) {
    return __builtin_amdgcn_mfma_f32_16x16x32_bf16(a, b, c, 0, 0, 0);
}
// 16B load from a 4B-aligned pointer (J odd -> bias rows only dword-aligned).
__device__ inline f32x4 loadu4(const float* p) {
    f32x4 r;
    __builtin_memcpy(&r, p, 16);
    return r;
}

// ---------------------------------------------------------------------------
// Kernel 0: fused prep. Block 0: mask sniff -> additive maskf[b][Jp].
// Block 1: zero pads of Kb/Vt. Block 2: null token -> Kb row 256 / Vt col 256.
__global__ void prep_all(const void* __restrict__ mraw, float* __restrict__ maskf,
                         unsigned short* __restrict__ Kb, unsigned short* __restrict__ Vt,
                         const float* __restrict__ nkv) {
    const int t = threadIdx.x;
    if (blockIdx.x == 0) {
        __shared__ int bad_int, bad_f32;
        if (t == 0) { bad_int = 0; bad_f32 = 0; }
        __syncthreads();
        const unsigned int* w = (const unsigned int*)mraw;
        int li = 0, lf = 0;
        for (int i = t; i < 1152; i += 256) {
            unsigned int v = w[i];
            if (v > 1u) li = 1;
            if (v != 0u && v != 0x3F800000u) lf = 1;
        }
        if (li) atomicOr(&bad_int, 1);
        if (lf) atomicOr(&bad_f32, 1);
        __syncthreads();
        const int mode = (!bad_int) ? 0 : ((!bad_f32) ? 1 : 2);
        const unsigned char* bytes = (const unsigned char*)mraw;
        for (int i = t; i < 2 * Jp; i += 256) {
            const int b2 = i / Jp, jp = i - b2 * Jp;
            float v;
            if (jp == 0) v = 0.f;
            else if (jp >= J) v = -1e30f;
            else {
                const int idx = b2 * (C + N) + jp - 1;
                const int keep = (mode == 2) ? (bytes[idx] != 0) : (w[idx] != 0u);
                v = keep ? 0.f : -1e30f;
            }
            maskf[i] = v;
        }
    } else if (blockIdx.x == 1) {
        for (int i = t; i < 2 * 63 * 64; i += 256) {
            const int b2 = i / (63 * 64);
            const int rr = (i / 64) % 63;
            const int d  = i % 64;
            Kb[(size_t)(b2 * Jp + J + rr) * 64 + d] = 0;
        }
        for (int i = t; i < 2 * 64 * 63; i += 256) {
            const int b2 = i / (64 * 63);
            const int d  = (i / 63) % 64;
            const int cc = i % 63;
            Vt[(size_t)(b2 * 64 + d) * Jp + J + cc] = 0;
        }
    } else {
        if (t < 128) {
            const int b2 = t >> 6, d = t & 63;
            Kb[(size_t)(b2 * Jp + 256) * 64 + d] = f2bf(nkv[d]);
            Vt[(size_t)(b2 * 64 + d) * Jp + 256] = f2bf(nkv[64 + d]);
        }
    }
}

// ---------------------------------------------------------------------------
// Kernel 2: layernorm over 1024 (beta=0). BF16OUT: write bf16, else f32.
template <int BF16OUT>
__global__ void __launch_bounds__(256) ln1024(const float* __restrict__ x,
                                              const float* __restrict__ gamma,
                                              void* __restrict__ outp) {
    const int row = blockIdx.x;
    const int t = threadIdx.x;
    const float* xr = x + (size_t)row * 1024;
    float4 v = ((const float4*)xr)[t];
    float s  = v.x + v.y + v.z + v.w;
    float ss = v.x * v.x + v.y * v.y + v.z * v.z + v.w * v.w;
    #pragma unroll
    for (int o = 1; o < 64; o <<= 1) {
        s  += __shfl_xor(s, o);
        ss += __shfl_xor(ss, o);
    }
    __shared__ float red[8];
    const int w = t >> 6;
    if ((t & 63) == 0) { red[w * 2] = s; red[w * 2 + 1] = ss; }
    __syncthreads();
    s  = red[0] + red[2] + red[4] + red[6];
    ss = red[1] + red[3] + red[5] + red[7];
    const float mean = s * (1.0f / 1024.0f);
    const float var  = ss * (1.0f / 1024.0f) - mean * mean;
    const float rstd = rsqrtf(var + EPS);
    const float4 g = ((const float4*)gamma)[t];
    float o0 = (v.x - mean) * rstd * g.x;
    float o1 = (v.y - mean) * rstd * g.y;
    float o2 = (v.z - mean) * rstd * g.z;
    float o3 = (v.w - mean) * rstd * g.w;
    if (BF16OUT) {
        ushort4 u;
        u.x = f2bf(o0); u.y = f2bf(o1); u.z = f2bf(o2); u.w = f2bf(o3);
        *(ushort4*)((unsigned short*)outp + (size_t)row * 1024 + t * 4) = u;
    } else {
        *(float4*)((float*)outp + (size_t)row * 1024 + t * 4) = make_float4(o0, o1, o2, o3);
    }
}

// ---------------------------------------------------------------------------
// Kernel 3: transpose + bf16-convert a weight W(K x Nn) -> WT(Nn x K), *scale.
__global__ void __launch_bounds__(256) transpose_w(const float* __restrict__ W,
                                                   unsigned short* __restrict__ WT,
                                                   int K, int Nn, float scale) {
    __shared__ float lds[64][68];
    const int k0 = blockIdx.x * 64, n0 = blockIdx.y * 64;
    const int t = threadIdx.x;
    const int kk = t >> 4, nn = (t & 15) * 4;
    #pragma unroll
    for (int r = 0; r < 4; r++) {
        const float4 v = *(const float4*)(W + (size_t)(k0 + kk + r * 16) * Nn + n0 + nn);
        lds[kk + r * 16][nn + 0] = v.x;
        lds[kk + r * 16][nn + 1] = v.y;
        lds[kk + r * 16][nn + 2] = v.z;
        lds[kk + r * 16][nn + 3] = v.w;
    }
    __syncthreads();
    const int nr = t >> 2, kc = (t & 3) * 16;
    #pragma unroll
    for (int u4 = 0; u4 < 4; u4++) {
        ushort4 u;
        u.x = f2bf(lds[kc + u4 * 4 + 0][nr] * scale);
        u.y = f2bf(lds[kc + u4 * 4 + 1][nr] * scale);
        u.z = f2bf(lds[kc + u4 * 4 + 2][nr] * scale);
        u.w = f2bf(lds[kc + u4 * 4 + 3][nr] * scale);
        *(ushort4*)(WT + (size_t)(n0 + nr) * K + k0 + kc + u4 * 4) = u;
    }
}

// ---------------------------------------------------------------------------
// Kernel 4: context path: LN(context,512) @ Wctx + bctx -> Kb[0..255] / Vt cols.
__global__ void __launch_bounds__(128) ctx_proj(const float* __restrict__ ctx,
                                                const float* __restrict__ lw,
                                                const float* __restrict__ lb,
                                                const float* __restrict__ Wc,
                                                const float* __restrict__ bc,
                                                unsigned short* __restrict__ Kb,
                                                unsigned short* __restrict__ Vt) {
    const int row = blockIdx.x;          // 0..511
    const int b2 = row >> 8, ci = row & 255;
    const int t = threadIdx.x;           // 0..127
    __shared__ float cn[512];
    __shared__ float red[4];
    const float* xr = ctx + (size_t)row * 512;
    float4 v = ((const float4*)xr)[t];
    float s  = v.x + v.y + v.z + v.w;
    float ss = v.x * v.x + v.y * v.y + v.z * v.z + v.w * v.w;
    #pragma unroll
    for (int o = 1; o < 64; o <<= 1) {
        s  += __shfl_xor(s, o);
        ss += __shfl_xor(ss, o);
    }
    const int w = t >> 6;
    if ((t & 63) == 0) { red[w * 2] = s; red[w * 2 + 1] = ss; }
    __syncthreads();
    s  = red[0] + red[2];
    ss = red[1] + red[3];
    const float mean = s * (1.0f / 512.0f);
    const float var  = ss * (1.0f / 512.0f) - mean * mean;
    const float rstd = rsqrtf(var + EPS);
    const float4 g  = ((const float4*)lw)[t];
    const float4 be = ((const float4*)lb)[t];
    float4 c4;
    c4.x = (v.x - mean) * rstd * g.x + be.x;
    c4.y = (v.y - mean) * rstd * g.y + be.y;
    c4.z = (v.z - mean) * rstd * g.z + be.z;
    c4.w = (v.w - mean) * rstd * g.w + be.w;
    *(float4*)&cn[t * 4] = c4;
    __syncthreads();
    float acc = bc[t];
    #pragma unroll 8
    for (int d = 0; d < 512; d++) acc = fmaf(cn[d], Wc[d * 128 + t], acc);
    const unsigned short bv = f2bf(acc);
    if (t < 64) Kb[(size_t)(b2 * Jp + ci) * 64 + t] = bv;
    else        Vt[(size_t)(b2 * 64 + (t - 64)) * Jp + ci] = bv;
}

// ---------------------------------------------------------------------------
// Kernel 6: bf16 MFMA GEMM, 128x128 tile, BK=64, 4 waves, 2-phase dbuf.
// A (M,K) bf16 row-major; BT (Nn,K) bf16 row-major (= B^T).
// MODE 0: Cf f32 [M,Nn].  MODE 1: Cb bf16 [M,Nn].  MODE 2: kv scatter.
template <int MODE>
__global__ void __launch_bounds__(256, 2) gemm_bf16(
        const unsigned short* __restrict__ A, const unsigned short* __restrict__ BT,
        float* __restrict__ Cf, unsigned short* __restrict__ Cb,
        unsigned short* __restrict__ Kb, unsigned short* __restrict__ Vt,
        int M, int Nn, int K) {
    __shared__ __align__(16) unsigned char smem[65536];
    const int t = threadIdx.x;
    const int w = t >> 6, lane = t & 63;
    const int g = lane >> 4, ln15 = lane & 15;
    const int wm = w >> 1, wn = w & 1;
    const int row0 = blockIdx.x * 128, col0 = blockIdx.y * 128;
    const int nk = K >> 6;
    const int ls = lane >> 3;
    const int swz = (lane & 7) ^ ls;

    f32x4 acc[4][4];
    #pragma unroll
    for (int i = 0; i < 4; i++)
        #pragma unroll
        for (int jj = 0; jj < 4; jj++)
            acc[i][jj] = (f32x4){0.f, 0.f, 0.f, 0.f};

    auto stage = [&](int kt, int cur) {
        if (w < 2) {
            const unsigned short* src = A + (size_t)(row0 + w * 64 + ls) * K + kt * 64 + swz * 8;
            unsigned char* dst = smem + cur * 16384 + w * 8192;
            #pragma unroll
            for (int i = 0; i < 8; i++)
                load_lds16(src + (size_t)i * 8 * K, dst + i * 1024);
        } else {
            const unsigned short* src = BT + (size_t)(col0 + (w - 2) * 64 + ls) * K + kt * 64 + swz * 8;
            unsigned char* dst = smem + 32768 + cur * 16384 + (w - 2) * 8192;
            #pragma unroll
            for (int i = 0; i < 8; i++)
                load_lds16(src + (size_t)i * 8 * K, dst + i * 1024);
        }
    };

    stage(0, 0);
    __syncthreads();
    for (int kt = 0; kt < nk; kt++) {
        const int cur = kt & 1;
        if (kt + 1 < nk) stage(kt + 1, cur ^ 1);
        const unsigned char* As = smem + cur * 16384;
        const unsigned char* Bs = smem + 32768 + cur * 16384;
        #pragma unroll
        for (int ks = 0; ks < 2; ks++) {
            bf16x8 af[4], bf[4];
            #pragma unroll
            for (int mq = 0; mq < 4; mq++)
                af[mq] = *(const bf16x8*)(As + (wm * 64 + mq * 16 + ln15) * 128 +
                                          ((ks * 64 + g * 16) ^ ((ln15 & 7) << 4)));
            #pragma unroll
            for (int nq = 0; nq < 4; nq++)
                bf[nq] = *(const bf16x8*)(Bs + (wn * 64 + nq * 16 + ln15) * 128 +
                                          ((ks * 64 + g * 16) ^ ((ln15 & 7) << 4)));
            #pragma unroll
            for (int mq = 0; mq < 4; mq++)
                #pragma unroll
                for (int nq = 0; nq < 4; nq++)
                    acc[mq][nq] = mfma16(af[mq], bf[nq], acc[mq][nq]);
        }
        __syncthreads();
    }

    #pragma unroll
    for (int mq = 0; mq < 4; mq++) {
        #pragma unroll
        for (int nq = 0; nq < 4; nq++) {
            #pragma unroll
            for (int r = 0; r < 4; r++) {
                const int gr = row0 + wm * 64 + mq * 16 + g * 4 + r;
                const int gc = col0 + wn * 64 + nq * 16 + ln15;
                if (MODE == 0) {
                    Cf[(size_t)gr * Nn + gc] = acc[mq][nq][r];
                } else if (MODE == 1) {
                    Cb[(size_t)gr * Nn + gc] = f2bf(acc[mq][nq][r]);
                } else {
                    const int b2 = gr >> 11, tok = gr & 2047;
                    const unsigned short v = f2bf(acc[mq][nq][r]);
                    if (gc < 64) Kb[(size_t)(b2 * Jp + 257 + tok) * 64 + gc] = v;
                    else         Vt[(size_t)(b2 * 64 + gc - 64) * Jp + 257 + tok] = v;
                }
            }
        }
    }
}

// ---------------------------------------------------------------------------
// Kernel 7: flash attention v13 — v8's mega-shared 1024-thread block, but
// SINGLE-buffered (KV 32 KB + bias 34 KB = 66 KB LDS) so TWO blocks
// co-reside per CU (launch_bounds(1024,8) -> 8 waves/SIMD). The two blocks
// are independent barrier streams: one block's stage/vmcnt drain overlaps
// the other's compute. Per-block structure identical to v8: 128 q-rows x
// both batches, K/V staged once per CU-tile, bias coalesced->LDS [128][68],
// swapped QK^T 16x16, exp2 domain, exact defer-rescale, cvt_pk pack, setprio.
__global__ void __launch_bounds__(1024, 8) attn_v13(
        const unsigned short* __restrict__ qb, const unsigned short* __restrict__ Kb,
        const unsigned short* __restrict__ Vt, const float* __restrict__ bias,
        const float* __restrict__ maskf, unsigned short* __restrict__ aout) {
    __shared__ __align__(16) unsigned char smem[67584];   // 32K KV + 34816 bias
    const int t = threadIdx.x;
    const int w = t >> 6, lane = t & 63;
    const int g = lane >> 4, ln15 = lane & 15;
    const int i0 = blockIdx.x * 128, h = blockIdx.y;
    const int b2 = w & 1, wq = w >> 1;            // wave: batch b2, q-rows i0+wq*16..+15
    const int ls = lane >> 3;
    const int swz = (lane & 7) ^ ls;

    // ---- K/V staging: 16 waves x 2 KB. Waves 0..7 stage K, 8..15 stage V.
    auto stage = [&](int jt) {
        const int j0 = jt * 64;
        const int quarter = w & 3;
        if (w < 8) {
            const int kb = (w >> 2) & 1;
            const unsigned short* src = Kb + (size_t)(kb * Jp + j0 + quarter * 16 + ls) * 64 + swz * 8;
            unsigned char* dst = smem + kb * 8192 + quarter * 2048;
            load_lds16(src, dst);
            load_lds16(src + (size_t)8 * 64, dst + 1024);
        } else {
            const int vb = (w >> 2) & 1;
            const unsigned short* src = Vt + (size_t)(vb * 64 + quarter * 16 + ls) * Jp + j0 + swz * 8;
            unsigned char* dst = smem + 16384 + vb * 8192 + quarter * 2048;
            load_lds16(src, dst);
            load_lds16(src + (size_t)8 * Jp, dst + 1024);
        }
    };

    // ---- Bias staging: [128 q][64 j] f32 -> LDS [128][68] (padded).
    const int bq  = t >> 3;          // 0..127: q-row this thread stages
    const int bs0 = t & 7;           // 16B slot (pass 0); pass 1 = +8
    const float* biasQrow = bias + ((size_t)h * N + i0 + bq) * J;
    auto bias_issue = [&](int jt, f32x4& r0, f32x4& r1) {
        const int j0 = jt * 64;
        if (j0 + 64 <= J) {
            r0 = loadu4(biasQrow + j0 + bs0 * 4);
            r1 = loadu4(biasQrow + j0 + (bs0 + 8) * 4);
        } else {
            #pragma unroll
            for (int c = 0; c < 4; c++) {
                const int jA = j0 + bs0 * 4 + c;
                const int jB = j0 + (bs0 + 8) * 4 + c;
                r0[c] = (jA < J) ? biasQrow[jA] : 0.f;
                r1[c] = (jB < J) ? biasQrow[jB] : 0.f;
            }
        }
    };
    auto bias_write = [&](const f32x4& r0, const f32x4& r1) {
        float* basep = (float*)(smem + 32768) + bq * 68;
        *(f32x4*)(basep + bs0 * 4) = r0;
        *(f32x4*)(basep + (bs0 + 8) * 4) = r1;
    };

    // Q fragments (B-operand of swapped QK^T): q-row = ln15, d k-contig.
    bf16x8 qf[2];
    #pragma unroll
    for (int ks = 0; ks < 2; ks++)
        qf[ks] = *(const bf16x8*)(qb + (size_t)(b2 * N + i0 + wq * 16 + ln15) * 1024 +
                                  h * 64 + ks * 32 + g * 8);

    float mrun = -1e30f, lrun = 0.f;
    f32x4 outA[4];
    #pragma unroll
    for (int nq = 0; nq < 4; nq++) outA[nq] = (f32x4){0.f, 0.f, 0.f, 0.f};

    const int srclA = ln15 + (((2 * g + 0) & 3) << 4);
    const int srclB = ln15 + (((2 * g + 1) & 3) << 4);

    auto compute = [&](int jt) {
        const int j0 = jt * 64;
        const unsigned char* Kl = smem + b2 * 8192;
        const unsigned char* Vl = smem + 16384 + b2 * 8192;
        const float* bb = (const float*)(smem + 32768) + (wq * 16 + ln15) * 68;

        f32x4 mk[4];
        #pragma unroll
        for (int jqm = 0; jqm < 4; jqm++)
            mk[jqm] = *(const f32x4*)(maskf + b2 * Jp + j0 + jqm * 16 + g * 4);
        f32x4 br[4];
        #pragma unroll
        for (int jqm = 0; jqm < 4; jqm++)
            br[jqm] = *(const f32x4*)(bb + (jqm * 4 + g) * 4);

        // S^T = K . Q : frag jqm rows j = j0+jqm*16+g*4+r, col q = ln15
        f32x4 S[4];
        #pragma unroll
        for (int jqm = 0; jqm < 4; jqm++) S[jqm] = (f32x4){0.f, 0.f, 0.f, 0.f};
        #pragma unroll
        for (int ks = 0; ks < 2; ks++) {
            bf16x8 ka[4];
            #pragma unroll
            for (int jqm = 0; jqm < 4; jqm++)
                ka[jqm] = *(const bf16x8*)(Kl + (jqm * 16 + ln15) * 128 +
                                           ((ks * 64 + g * 16) ^ ((ln15 & 7) << 4)));
            __builtin_amdgcn_s_setprio(1);
            #pragma unroll
            for (int jqm = 0; jqm < 4; jqm++)
                S[jqm] = mfma16(ka[jqm], qf[ks], S[jqm]);
            __builtin_amdgcn_s_setprio(0);
        }

        // log2 domain: S pre-scaled by log2e (via Wq), bias*log2e via fma
        float sv[4][4];
        #pragma unroll
        for (int jqm = 0; jqm < 4; jqm++)
            #pragma unroll
            for (int r = 0; r < 4; r++)
                sv[jqm][r] = fmaf(br[jqm][r], LOG2E, S[jqm][r]) + mk[jqm][r];

        float tmj[4];
        #pragma unroll
        for (int jqm = 0; jqm < 4; jqm++)
            tmj[jqm] = fmaxf(fmaxf(sv[jqm][0], sv[jqm][1]), fmaxf(sv[jqm][2], sv[jqm][3]));
        float tm = fmaxf(fmaxf(tmj[0], tmj[1]), fmaxf(tmj[2], tmj[3]));
        tm = fmaxf(tm, __shfl_xor(tm, 16));
        tm = fmaxf(tm, __shfl_xor(tm, 32));

        if (!__all(tm <= mrun)) {      // exact skip: rescale only if max grew
            const float mnew = fmaxf(mrun, tm);
            const float cor = fexp2(mrun - mnew);
            mrun = mnew;
            float corr[4];
            #pragma unroll
            for (int r = 0; r < 4; r++) corr[r] = __shfl(cor, g * 4 + r, 64);
            #pragma unroll
            for (int nq = 0; nq < 4; nq++)
                #pragma unroll
                for (int r = 0; r < 4; r++)
                    outA[nq][r] *= corr[r];
            lrun *= cor;
        }
        const float mcur = mrun;

        float p[4][4];
        #pragma unroll
        for (int jqm = 0; jqm < 4; jqm++)
            #pragma unroll
            for (int r = 0; r < 4; r++)
                p[jqm][r] = fexp2(sv[jqm][r] - mcur);
        float tsj[4];
        #pragma unroll
        for (int jqm = 0; jqm < 4; jqm++)
            tsj[jqm] = (p[jqm][0] + p[jqm][1]) + (p[jqm][2] + p[jqm][3]);
        float ts = (tsj[0] + tsj[1]) + (tsj[2] + tsj[3]);
        ts += __shfl_xor(ts, 16);
        ts += __shfl_xor(ts, 32);
        lrun += ts;

        unsigned int Wp[4][2];
        #pragma unroll
        for (int jqm = 0; jqm < 4; jqm++) {
            Wp[jqm][0] = packbf2(p[jqm][0], p[jqm][1]);
            Wp[jqm][1] = packbf2(p[jqm][2], p[jqm][3]);
        }

        // repack to PV A-fragments: lane needs P[q=ln15][j=ks*32+g*8+0..7]
        #pragma unroll
        for (int ks = 0; ks < 2; ks++) {
            uint4v wd;
            #pragma unroll
            for (int widx = 0; widx < 4; widx++) {
                const int srcl = (widx >> 1) ? srclB : srclA;
                const int t0 = __shfl((int)Wp[ks * 2 + 0][widx & 1], srcl, 64);
                const int t1 = __shfl((int)Wp[ks * 2 + 1][widx & 1], srcl, 64);
                wd[widx] = (unsigned int)((g >> 1) ? t1 : t0);
            }
            const bf16x8 pa = __builtin_bit_cast(bf16x8, wd);
            bf16x8 vf[4];
            #pragma unroll
            for (int nq = 0; nq < 4; nq++)
                vf[nq] = *(const bf16x8*)(Vl + (nq * 16 + ln15) * 128 +
                                          ((ks * 64 + g * 16) ^ ((ln15 & 7) << 4)));
            __builtin_amdgcn_s_setprio(1);
            #pragma unroll
            for (int nq = 0; nq < 4; nq++)
                outA[nq] = mfma16(pa, vf[nq], outA[nq]);
            __builtin_amdgcn_s_setprio(0);
        }
    };

    // ---- single-buffered loop; the co-resident second block overlaps the
    // stage/bias drain at barrier 1 with its own compute phase.
    for (int jt = 0; jt < NT; jt++) {
        f32x4 bR0, bR1;
        bias_issue(jt, bR0, bR1);
        stage(jt);
        bias_write(bR0, bR1);      // vmcnt wait for bR only (counted)
        __syncthreads();           // K/V + bias LDS ready
        compute(jt);
        __syncthreads();           // all reads of this tile done
    }

    const float inv = 1.0f / lrun;
    float invr[4];
    #pragma unroll
    for (int r = 0; r < 4; r++) invr[r] = __shfl(inv, g * 4 + r, 64);
    #pragma unroll
    for (int nq = 0; nq < 4; nq++)
        #pragma unroll
        for (int r = 0; r < 4; r++)
            aout[(size_t)(b2 * N + i0 + wq * 16 + g * 4 + r) * 1024 +
                 h * 64 + nq * 16 + ln15] = f2bf(outA[nq][r] * invr[r]);
}

// ---------------------------------------------------------------------------
extern "C" void kernel_launch(void* const* d_in, const int* in_sizes, int n_in,
                              void* d_out, int out_size, void* d_ws, size_t ws_size,
                              hipStream_t stream) {
    const float* x         = (const float*)d_in[0];
    const float* context   = (const float*)d_in[1];
    const void*  mask      = d_in[2];
    const float* bias      = (const float*)d_in[3];
    const float* norm_g    = (const float*)d_in[4];
    const float* null_kv   = (const float*)d_in[5];
    const float* Wq        = (const float*)d_in[6];
    const float* Wkv       = (const float*)d_in[7];
    const float* ctx_ln_w  = (const float*)d_in[8];
    const float* ctx_ln_b  = (const float*)d_in[9];
    const float* Wctx      = (const float*)d_in[10];
    const float* bctx      = (const float*)d_in[11];
    const float* Wout      = (const float*)d_in[12];
    const float* out_gamma = (const float*)d_in[13];
    float* out = (float*)d_out;

    unsigned char* wsb = (unsigned char*)d_ws;
    unsigned short* xnb   = (unsigned short*)(wsb + 0);          //  8 MB bf16
    unsigned short* qbb   = (unsigned short*)(wsb + 8388608);    //  8 MB bf16
    float*          y     = (float*)(wsb + 0);                   // 16 MB f32 (overlays xnb+qbb, both dead)
    unsigned short* aoutp = (unsigned short*)(wsb + 16777216);   //  8 MB bf16
    unsigned short* KbP   = (unsigned short*)(wsb + 25165824);   // 2*Jp*64 bf16
    unsigned short* VtP   = (unsigned short*)(wsb + 25772032);   // 2*64*Jp bf16
    float*          maskf = (float*)(wsb + 26378240);            // 2*Jp f32
    unsigned short* WqT   = (unsigned short*)(wsb + 26397184);   // 2 MB
    unsigned short* WkvT  = (unsigned short*)(wsb + 28494336);   // 256 KB
    unsigned short* WoutT = (unsigned short*)(wsb + 28756480);   // 2 MB

    prep_all<<<3, 256, 0, stream>>>(mask, maskf, KbP, VtP, null_kv);
    ln1024<1><<<B * N, 256, 0, stream>>>(x, norm_g, xnb);
    // fold Dh^-0.5 * log2e into Wq so attention works in exp2 domain
    transpose_w<<<dim3(16, 16), 256, 0, stream>>>(Wq, WqT, 1024, 1024, 0.125f * LOG2E);
    transpose_w<<<dim3(16, 2), 256, 0, stream>>>(Wkv, WkvT, 1024, 128, 1.0f);
    transpose_w<<<dim3(16, 16), 256, 0, stream>>>(Wout, WoutT, 1024, 1024, 1.0f);
    ctx_proj<<<B * C, 128, 0, stream>>>(context, ctx_ln_w, ctx_ln_b, Wctx, bctx, KbP, VtP);
    // q = LN(x) @ (Wq*scale) -> bf16 (4096 x 1024)
    gemm_bf16<1><<<dim3(32, 8), 256, 0, stream>>>(xnb, WqT, nullptr, qbb, nullptr, nullptr, 4096, 1024, 1024);
    // k,v = LN(x) @ Wkv -> scatter bf16 into Kb rows / Vt cols 257..2304
    gemm_bf16<2><<<dim3(32, 1), 256, 0, stream>>>(xnb, WkvT, nullptr, nullptr, KbP, VtP, 4096, 128, 1024);
    attn_v13<<<dim3(16, 16), 1024, 0, stream>>>(qbb, KbP, VtP, bias, maskf, aoutp);
    // y = attn_out @ Wout -> f32
    gemm_bf16<0><<<dim3(32, 8), 256, 0, stream>>>(aoutp, WoutT, y, nullptr, nullptr, nullptr, 4096, 1024, 1024);
    ln1024<0><<<B * N, 256, 0, stream>>>(y, out_gamma, out);
}

// Round 14
// 263.287 us; speedup vs baseline: 2.9258x; 2.9258x over previous
//
#include <hip/hip_runtime.h>

// Problem constants
constexpr int B  = 2;
constexpr int N  = 2048;
constexpr int H  = 16;
constexpr int C  = 256;
constexpr int J  = C + 1 + N;    // 2305
constexpr int Jp = 2368;         // J padded to multiple of 64
constexpr int NT = Jp / 64;      // 37 j-tiles
constexpr float EPS = 1e-5f;
constexpr float LOG2E = 1.4426950408889634f;

typedef __bf16 bf16x8 __attribute__((ext_vector_type(8)));
typedef float  f32x4  __attribute__((ext_vector_type(4)));
typedef unsigned int uint4v __attribute__((ext_vector_type(4)));
typedef __attribute__((address_space(3))) unsigned int lds_u32;
typedef const __attribute__((address_space(1))) unsigned int glb_u32;

__device__ inline void load_lds16(const void* g, void* l) {
    __builtin_amdgcn_global_load_lds((glb_u32*)g, (lds_u32*)l, 16, 0, 0);
}
__device__ inline unsigned short f2bf(float f) {
    unsigned int u = __builtin_bit_cast(unsigned int, f);
    u += 0x7fffu + ((u >> 16) & 1u);
    return (unsigned short)(u >> 16);
}
__device__ inline unsigned int packbf2(float a, float b) {
    union { __bf16 h[2]; unsigned int u; } cv;
    cv.h[0] = (__bf16)a;
    cv.h[1] = (__bf16)b;
    return cv.u;
}
__device__ inline float fexp2(float x) {
    float r;
    asm("v_exp_f32 %0, %1" : "=v"(r) : "v"(x));
    return r;
}
__device__ inline f32x4 mfma16(bf16x8 a, bf16x8 b, f32x4 c) {
    return __builtin_amdgcn_mfma_f32_16x16x32_bf16(a, b, c, 0, 0, 0);
}
// 16B load from a 4B-aligned pointer (J odd -> bias rows only dword-aligned).
__device__ inline f32x4 loadu4(const float* p) {
    f32x4 r;
    __builtin_memcpy(&r, p, 16);
    return r;
}

// ---------------------------------------------------------------------------
// Kernel 0: fused prep. Block 0: mask sniff -> additive maskf[b][Jp].
// Block 1: zero pads of Kb/Vt. Block 2: null token -> Kb row 256 / Vt col 256.
__global__ void prep_all(const void* __restrict__ mraw, float* __restrict__ maskf,
                         unsigned short* __restrict__ Kb, unsigned short* __restrict__ Vt,
                         const float* __restrict__ nkv) {
    const int t = threadIdx.x;
    if (blockIdx.x == 0) {
        __shared__ int bad_int, bad_f32;
        if (t == 0) { bad_int = 0; bad_f32 = 0; }
        __syncthreads();
        const unsigned int* w = (const unsigned int*)mraw;
        int li = 0, lf = 0;
        for (int i = t; i < 1152; i += 256) {
            unsigned int v = w[i];
            if (v > 1u) li = 1;
            if (v != 0u && v != 0x3F800000u) lf = 1;
        }
        if (li) atomicOr(&bad_int, 1);
        if (lf) atomicOr(&bad_f32, 1);
        __syncthreads();
        const int mode = (!bad_int) ? 0 : ((!bad_f32) ? 1 : 2);
        const unsigned char* bytes = (const unsigned char*)mraw;
        for (int i = t; i < 2 * Jp; i += 256) {
            const int b2 = i / Jp, jp = i - b2 * Jp;
            float v;
            if (jp == 0) v = 0.f;
            else if (jp >= J) v = -1e30f;
            else {
                const int idx = b2 * (C + N) + jp - 1;
                const int keep = (mode == 2) ? (bytes[idx] != 0) : (w[idx] != 0u);
                v = keep ? 0.f : -1e30f;
            }
            maskf[i] = v;
        }
    } else if (blockIdx.x == 1) {
        for (int i = t; i < 2 * 63 * 64; i += 256) {
            const int b2 = i / (63 * 64);
            const int rr = (i / 64) % 63;
            const int d  = i % 64;
            Kb[(size_t)(b2 * Jp + J + rr) * 64 + d] = 0;
        }
        for (int i = t; i < 2 * 64 * 63; i += 256) {
            const int b2 = i / (64 * 63);
            const int d  = (i / 63) % 64;
            const int cc = i % 63;
            Vt[(size_t)(b2 * 64 + d) * Jp + J + cc] = 0;
        }
    } else {
        if (t < 128) {
            const int b2 = t >> 6, d = t & 63;
            Kb[(size_t)(b2 * Jp + 256) * 64 + d] = f2bf(nkv[d]);
            Vt[(size_t)(b2 * 64 + d) * Jp + 256] = f2bf(nkv[64 + d]);
        }
    }
}

// ---------------------------------------------------------------------------
// Kernel 2: layernorm over 1024 (beta=0). BF16OUT: write bf16, else f32.
template <int BF16OUT>
__global__ void __launch_bounds__(256) ln1024(const float* __restrict__ x,
                                              const float* __restrict__ gamma,
                                              void* __restrict__ outp) {
    const int row = blockIdx.x;
    const int t = threadIdx.x;
    const float* xr = x + (size_t)row * 1024;
    float4 v = ((const float4*)xr)[t];
    float s  = v.x + v.y + v.z + v.w;
    float ss = v.x * v.x + v.y * v.y + v.z * v.z + v.w * v.w;
    #pragma unroll
    for (int o = 1; o < 64; o <<= 1) {
        s  += __shfl_xor(s, o);
        ss += __shfl_xor(ss, o);
    }
    __shared__ float red[8];
    const int w = t >> 6;
    if ((t & 63) == 0) { red[w * 2] = s; red[w * 2 + 1] = ss; }
    __syncthreads();
    s  = red[0] + red[2] + red[4] + red[6];
    ss = red[1] + red[3] + red[5] + red[7];
    const float mean = s * (1.0f / 1024.0f);
    const float var  = ss * (1.0f / 1024.0f) - mean * mean;
    const float rstd = rsqrtf(var + EPS);
    const float4 g = ((const float4*)gamma)[t];
    float o0 = (v.x - mean) * rstd * g.x;
    float o1 = (v.y - mean) * rstd * g.y;
    float o2 = (v.z - mean) * rstd * g.z;
    float o3 = (v.w - mean) * rstd * g.w;
    if (BF16OUT) {
        ushort4 u;
        u.x = f2bf(o0); u.y = f2bf(o1); u.z = f2bf(o2); u.w = f2bf(o3);
        *(ushort4*)((unsigned short*)outp + (size_t)row * 1024 + t * 4) = u;
    } else {
        *(float4*)((float*)outp + (size_t)row * 1024 + t * 4) = make_float4(o0, o1, o2, o3);
    }
}

// ---------------------------------------------------------------------------
// Kernel 3: transpose + bf16-convert a weight W(K x Nn) -> WT(Nn x K), *scale.
__global__ void __launch_bounds__(256) transpose_w(const float* __restrict__ W,
                                                   unsigned short* __restrict__ WT,
                                                   int K, int Nn, float scale) {
    __shared__ float lds[64][68];
    const int k0 = blockIdx.x * 64, n0 = blockIdx.y * 64;
    const int t = threadIdx.x;
    const int kk = t >> 4, nn = (t & 15) * 4;
    #pragma unroll
    for (int r = 0; r < 4; r++) {
        const float4 v = *(const float4*)(W + (size_t)(k0 + kk + r * 16) * Nn + n0 + nn);
        lds[kk + r * 16][nn + 0] = v.x;
        lds[kk + r * 16][nn + 1] = v.y;
        lds[kk + r * 16][nn + 2] = v.z;
        lds[kk + r * 16][nn + 3] = v.w;
    }
    __syncthreads();
    const int nr = t >> 2, kc = (t & 3) * 16;
    #pragma unroll
    for (int u4 = 0; u4 < 4; u4++) {
        ushort4 u;
        u.x = f2bf(lds[kc + u4 * 4 + 0][nr] * scale);
        u.y = f2bf(lds[kc + u4 * 4 + 1][nr] * scale);
        u.z = f2bf(lds[kc + u4 * 4 + 2][nr] * scale);
        u.w = f2bf(lds[kc + u4 * 4 + 3][nr] * scale);
        *(ushort4*)(WT + (size_t)(n0 + nr) * K + k0 + kc + u4 * 4) = u;
    }
}

// ---------------------------------------------------------------------------
// Kernel 4: context path: LN(context,512) @ Wctx + bctx -> Kb[0..255] / Vt cols.
__global__ void __launch_bounds__(128) ctx_proj(const float* __restrict__ ctx,
                                                const float* __restrict__ lw,
                                                const float* __restrict__ lb,
                                                const float* __restrict__ Wc,
                                                const float* __restrict__ bc,
                                                unsigned short* __restrict__ Kb,
                                                unsigned short* __restrict__ Vt) {
    const int row = blockIdx.x;          // 0..511
    const int b2 = row >> 8, ci = row & 255;
    const int t = threadIdx.x;           // 0..127
    __shared__ float cn[512];
    __shared__ float red[4];
    const float* xr = ctx + (size_t)row * 512;
    float4 v = ((const float4*)xr)[t];
    float s  = v.x + v.y + v.z + v.w;
    float ss = v.x * v.x + v.y * v.y + v.z * v.z + v.w * v.w;
    #pragma unroll
    for (int o = 1; o < 64; o <<= 1) {
        s  += __shfl_xor(s, o);
        ss += __shfl_xor(ss, o);
    }
    const int w = t >> 6;
    if ((t & 63) == 0) { red[w * 2] = s; red[w * 2 + 1] = ss; }
    __syncthreads();
    s  = red[0] + red[2];
    ss = red[1] + red[3];
    const float mean = s * (1.0f / 512.0f);
    const float var  = ss * (1.0f / 512.0f) - mean * mean;
    const float rstd = rsqrtf(var + EPS);
    const float4 g  = ((const float4*)lw)[t];
    const float4 be = ((const float4*)lb)[t];
    float4 c4;
    c4.x = (v.x - mean) * rstd * g.x + be.x;
    c4.y = (v.y - mean) * rstd * g.y + be.y;
    c4.z = (v.z - mean) * rstd * g.z + be.z;
    c4.w = (v.w - mean) * rstd * g.w + be.w;
    *(float4*)&cn[t * 4] = c4;
    __syncthreads();
    float acc = bc[t];
    #pragma unroll 8
    for (int d = 0; d < 512; d++) acc = fmaf(cn[d], Wc[d * 128 + t], acc);
    const unsigned short bv = f2bf(acc);
    if (t < 64) Kb[(size_t)(b2 * Jp + ci) * 64 + t] = bv;
    else        Vt[(size_t)(b2 * 64 + (t - 64)) * Jp + ci] = bv;
}

// ---------------------------------------------------------------------------
// Kernel 6: bf16 MFMA GEMM, 128x128 tile, BK=64, 4 waves, 2-phase dbuf.
// A (M,K) bf16 row-major; BT (Nn,K) bf16 row-major (= B^T).
// MODE 0: Cf f32 [M,Nn].  MODE 1: Cb bf16 [M,Nn].  MODE 2: kv scatter.
template <int MODE>
__global__ void __launch_bounds__(256, 2) gemm_bf16(
        const unsigned short* __restrict__ A, const unsigned short* __restrict__ BT,
        float* __restrict__ Cf, unsigned short* __restrict__ Cb,
        unsigned short* __restrict__ Kb, unsigned short* __restrict__ Vt,
        int M, int Nn, int K) {
    __shared__ __align__(16) unsigned char smem[65536];
    const int t = threadIdx.x;
    const int w = t >> 6, lane = t & 63;
    const int g = lane >> 4, ln15 = lane & 15;
    const int wm = w >> 1, wn = w & 1;
    const int row0 = blockIdx.x * 128, col0 = blockIdx.y * 128;
    const int nk = K >> 6;
    const int ls = lane >> 3;
    const int swz = (lane & 7) ^ ls;

    f32x4 acc[4][4];
    #pragma unroll
    for (int i = 0; i < 4; i++)
        #pragma unroll
        for (int jj = 0; jj < 4; jj++)
            acc[i][jj] = (f32x4){0.f, 0.f, 0.f, 0.f};

    auto stage = [&](int kt, int cur) {
        if (w < 2) {
            const unsigned short* src = A + (size_t)(row0 + w * 64 + ls) * K + kt * 64 + swz * 8;
            unsigned char* dst = smem + cur * 16384 + w * 8192;
            #pragma unroll
            for (int i = 0; i < 8; i++)
                load_lds16(src + (size_t)i * 8 * K, dst + i * 1024);
        } else {
            const unsigned short* src = BT + (size_t)(col0 + (w - 2) * 64 + ls) * K + kt * 64 + swz * 8;
            unsigned char* dst = smem + 32768 + cur * 16384 + (w - 2) * 8192;
            #pragma unroll
            for (int i = 0; i < 8; i++)
                load_lds16(src + (size_t)i * 8 * K, dst + i * 1024);
        }
    };

    stage(0, 0);
    __syncthreads();
    for (int kt = 0; kt < nk; kt++) {
        const int cur = kt & 1;
        if (kt + 1 < nk) stage(kt + 1, cur ^ 1);
        const unsigned char* As = smem + cur * 16384;
        const unsigned char* Bs = smem + 32768 + cur * 16384;
        #pragma unroll
        for (int ks = 0; ks < 2; ks++) {
            bf16x8 af[4], bf[4];
            #pragma unroll
            for (int mq = 0; mq < 4; mq++)
                af[mq] = *(const bf16x8*)(As + (wm * 64 + mq * 16 + ln15) * 128 +
                                          ((ks * 64 + g * 16) ^ ((ln15 & 7) << 4)));
            #pragma unroll
            for (int nq = 0; nq < 4; nq++)
                bf[nq] = *(const bf16x8*)(Bs + (wn * 64 + nq * 16 + ln15) * 128 +
                                          ((ks * 64 + g * 16) ^ ((ln15 & 7) << 4)));
            #pragma unroll
            for (int mq = 0; mq < 4; mq++)
                #pragma unroll
                for (int nq = 0; nq < 4; nq++)
                    acc[mq][nq] = mfma16(af[mq], bf[nq], acc[mq][nq]);
        }
        __syncthreads();
    }

    #pragma unroll
    for (int mq = 0; mq < 4; mq++) {
        #pragma unroll
        for (int nq = 0; nq < 4; nq++) {
            #pragma unroll
            for (int r = 0; r < 4; r++) {
                const int gr = row0 + wm * 64 + mq * 16 + g * 4 + r;
                const int gc = col0 + wn * 64 + nq * 16 + ln15;
                if (MODE == 0) {
                    Cf[(size_t)gr * Nn + gc] = acc[mq][nq][r];
                } else if (MODE == 1) {
                    Cb[(size_t)gr * Nn + gc] = f2bf(acc[mq][nq][r]);
                } else {
                    const int b2 = gr >> 11, tok = gr & 2047;
                    const unsigned short v = f2bf(acc[mq][nq][r]);
                    if (gc < 64) Kb[(size_t)(b2 * Jp + 257 + tok) * 64 + gc] = v;
                    else         Vt[(size_t)(b2 * 64 + gc - 64) * Jp + 257 + tok] = v;
                }
            }
        }
    }
}

// ---------------------------------------------------------------------------
// Kernel 7: flash attention v14 — v13 structure (single-buffered 66 KB LDS,
// two 1024-thread blocks can co-reside per CU) but with launch_bounds(1024,4)
// so the register allocator is NOT squeezed (v8's identical body compiled to
// 64 VGPR under this bound; 64 VGPR permits 8 waves/SIMD, so residency is
// limited by actual usage, not the bound). One block's stage/vmcnt drain
// overlaps the co-resident block's compute phase.
__global__ void __launch_bounds__(1024, 4) attn_v14(
        const unsigned short* __restrict__ qb, const unsigned short* __restrict__ Kb,
        const unsigned short* __restrict__ Vt, const float* __restrict__ bias,
        const float* __restrict__ maskf, unsigned short* __restrict__ aout) {
    __shared__ __align__(16) unsigned char smem[67584];   // 32K KV + 34816 bias
    const int t = threadIdx.x;
    const int w = t >> 6, lane = t & 63;
    const int g = lane >> 4, ln15 = lane & 15;
    const int i0 = blockIdx.x * 128, h = blockIdx.y;
    const int b2 = w & 1, wq = w >> 1;            // wave: batch b2, q-rows i0+wq*16..+15
    const int ls = lane >> 3;
    const int swz = (lane & 7) ^ ls;

    // ---- K/V staging: 16 waves x 2 KB. Waves 0..7 stage K, 8..15 stage V.
    auto stage = [&](int jt) {
        const int j0 = jt * 64;
        const int quarter = w & 3;
        if (w < 8) {
            const int kb = (w >> 2) & 1;
            const unsigned short* src = Kb + (size_t)(kb * Jp + j0 + quarter * 16 + ls) * 64 + swz * 8;
            unsigned char* dst = smem + kb * 8192 + quarter * 2048;
            load_lds16(src, dst);
            load_lds16(src + (size_t)8 * 64, dst + 1024);
        } else {
            const int vb = (w >> 2) & 1;
            const unsigned short* src = Vt + (size_t)(vb * 64 + quarter * 16 + ls) * Jp + j0 + swz * 8;
            unsigned char* dst = smem + 16384 + vb * 8192 + quarter * 2048;
            load_lds16(src, dst);
            load_lds16(src + (size_t)8 * Jp, dst + 1024);
        }
    };

    // ---- Bias staging: [128 q][64 j] f32 -> LDS [128][68] (padded).
    const int bq  = t >> 3;          // 0..127: q-row this thread stages
    const int bs0 = t & 7;           // 16B slot (pass 0); pass 1 = +8
    const float* biasQrow = bias + ((size_t)h * N + i0 + bq) * J;
    auto bias_issue = [&](int jt, f32x4& r0, f32x4& r1) {
        const int j0 = jt * 64;
        if (j0 + 64 <= J) {
            r0 = loadu4(biasQrow + j0 + bs0 * 4);
            r1 = loadu4(biasQrow + j0 + (bs0 + 8) * 4);
        } else {
            #pragma unroll
            for (int c = 0; c < 4; c++) {
                const int jA = j0 + bs0 * 4 + c;
                const int jB = j0 + (bs0 + 8) * 4 + c;
                r0[c] = (jA < J) ? biasQrow[jA] : 0.f;
                r1[c] = (jB < J) ? biasQrow[jB] : 0.f;
            }
        }
    };
    auto bias_write = [&](const f32x4& r0, const f32x4& r1) {
        float* basep = (float*)(smem + 32768) + bq * 68;
        *(f32x4*)(basep + bs0 * 4) = r0;
        *(f32x4*)(basep + (bs0 + 8) * 4) = r1;
    };

    // Q fragments (B-operand of swapped QK^T): q-row = ln15, d k-contig.
    bf16x8 qf[2];
    #pragma unroll
    for (int ks = 0; ks < 2; ks++)
        qf[ks] = *(const bf16x8*)(qb + (size_t)(b2 * N + i0 + wq * 16 + ln15) * 1024 +
                                  h * 64 + ks * 32 + g * 8);

    float mrun = -1e30f, lrun = 0.f;
    f32x4 outA[4];
    #pragma unroll
    for (int nq = 0; nq < 4; nq++) outA[nq] = (f32x4){0.f, 0.f, 0.f, 0.f};

    const int srclA = ln15 + (((2 * g + 0) & 3) << 4);
    const int srclB = ln15 + (((2 * g + 1) & 3) << 4);

    auto compute = [&](int jt) {
        const int j0 = jt * 64;
        const unsigned char* Kl = smem + b2 * 8192;
        const unsigned char* Vl = smem + 16384 + b2 * 8192;
        const float* bb = (const float*)(smem + 32768) + (wq * 16 + ln15) * 68;

        f32x4 mk[4];
        #pragma unroll
        for (int jqm = 0; jqm < 4; jqm++)
            mk[jqm] = *(const f32x4*)(maskf + b2 * Jp + j0 + jqm * 16 + g * 4);
        f32x4 br[4];
        #pragma unroll
        for (int jqm = 0; jqm < 4; jqm++)
            br[jqm] = *(const f32x4*)(bb + (jqm * 4 + g) * 4);

        // S^T = K . Q : frag jqm rows j = j0+jqm*16+g*4+r, col q = ln15
        f32x4 S[4];
        #pragma unroll
        for (int jqm = 0; jqm < 4; jqm++) S[jqm] = (f32x4){0.f, 0.f, 0.f, 0.f};
        #pragma unroll
        for (int ks = 0; ks < 2; ks++) {
            bf16x8 ka[4];
            #pragma unroll
            for (int jqm = 0; jqm < 4; jqm++)
                ka[jqm] = *(const bf16x8*)(Kl + (jqm * 16 + ln15) * 128 +
                                           ((ks * 64 + g * 16) ^ ((ln15 & 7) << 4)));
            __builtin_amdgcn_s_setprio(1);
            #pragma unroll
            for (int jqm = 0; jqm < 4; jqm++)
                S[jqm] = mfma16(ka[jqm], qf[ks], S[jqm]);
            __builtin_amdgcn_s_setprio(0);
        }

        // log2 domain: S pre-scaled by log2e (via Wq), bias*log2e via fma
        float sv[4][4];
        #pragma unroll
        for (int jqm = 0; jqm < 4; jqm++)
            #pragma unroll
            for (int r = 0; r < 4; r++)
                sv[jqm][r] = fmaf(br[jqm][r], LOG2E, S[jqm][r]) + mk[jqm][r];

        float tmj[4];
        #pragma unroll
        for (int jqm = 0; jqm < 4; jqm++)
            tmj[jqm] = fmaxf(fmaxf(sv[jqm][0], sv[jqm][1]), fmaxf(sv[jqm][2], sv[jqm][3]));
        float tm = fmaxf(fmaxf(tmj[0], tmj[1]), fmaxf(tmj[2], tmj[3]));
        tm = fmaxf(tm, __shfl_xor(tm, 16));
        tm = fmaxf(tm, __shfl_xor(tm, 32));

        if (!__all(tm <= mrun)) {      // exact skip: rescale only if max grew
            const float mnew = fmaxf(mrun, tm);
            const float cor = fexp2(mrun - mnew);
            mrun = mnew;
            float corr[4];
            #pragma unroll
            for (int r = 0; r < 4; r++) corr[r] = __shfl(cor, g * 4 + r, 64);
            #pragma unroll
            for (int nq = 0; nq < 4; nq++)
                #pragma unroll
                for (int r = 0; r < 4; r++)
                    outA[nq][r] *= corr[r];
            lrun *= cor;
        }
        const float mcur = mrun;

        float p[4][4];
        #pragma unroll
        for (int jqm = 0; jqm < 4; jqm++)
            #pragma unroll
            for (int r = 0; r < 4; r++)
                p[jqm][r] = fexp2(sv[jqm][r] - mcur);
        float tsj[4];
        #pragma unroll
        for (int jqm = 0; jqm < 4; jqm++)
            tsj[jqm] = (p[jqm][0] + p[jqm][1]) + (p[jqm][2] + p[jqm][3]);
        float ts = (tsj[0] + tsj[1]) + (tsj[2] + tsj[3]);
        ts += __shfl_xor(ts, 16);
        ts += __shfl_xor(ts, 32);
        lrun += ts;

        unsigned int Wp[4][2];
        #pragma unroll
        for (int jqm = 0; jqm < 4; jqm++) {
            Wp[jqm][0] = packbf2(p[jqm][0], p[jqm][1]);
            Wp[jqm][1] = packbf2(p[jqm][2], p[jqm][3]);
        }

        // repack to PV A-fragments: lane needs P[q=ln15][j=ks*32+g*8+0..7]
        #pragma unroll
        for (int ks = 0; ks < 2; ks++) {
            uint4v wd;
            #pragma unroll
            for (int widx = 0; widx < 4; widx++) {
                const int srcl = (widx >> 1) ? srclB : srclA;
                const int t0 = __shfl((int)Wp[ks * 2 + 0][widx & 1], srcl, 64);
                const int t1 = __shfl((int)Wp[ks * 2 + 1][widx & 1], srcl, 64);
                wd[widx] = (unsigned int)((g >> 1) ? t1 : t0);
            }
            const bf16x8 pa = __builtin_bit_cast(bf16x8, wd);
            bf16x8 vf[4];
            #pragma unroll
            for (int nq = 0; nq < 4; nq++)
                vf[nq] = *(const bf16x8*)(Vl + (nq * 16 + ln15) * 128 +
                                          ((ks * 64 + g * 16) ^ ((ln15 & 7) << 4)));
            __builtin_amdgcn_s_setprio(1);
            #pragma unroll
            for (int nq = 0; nq < 4; nq++)
                outA[nq] = mfma16(pa, vf[nq], outA[nq]);
            __builtin_amdgcn_s_setprio(0);
        }
    };

    // ---- single-buffered loop; the co-resident second block overlaps the
    // stage/bias drain at barrier 1 with its own compute phase.
    for (int jt = 0; jt < NT; jt++) {
        f32x4 bR0, bR1;
        bias_issue(jt, bR0, bR1);
        stage(jt);
        bias_write(bR0, bR1);      // vmcnt wait for bR only (counted)
        __syncthreads();           // K/V + bias LDS ready
        compute(jt);
        __syncthreads();           // all reads of this tile done
    }

    const float inv = 1.0f / lrun;
    float invr[4];
    #pragma unroll
    for (int r = 0; r < 4; r++) invr[r] = __shfl(inv, g * 4 + r, 64);
    #pragma unroll
    for (int nq = 0; nq < 4; nq++)
        #pragma unroll
        for (int r = 0; r < 4; r++)
            aout[(size_t)(b2 * N + i0 + wq * 16 + g * 4 + r) * 1024 +
                 h * 64 + nq * 16 + ln15] = f2bf(outA[nq][r] * invr[r]);
}

// ---------------------------------------------------------------------------
extern "C" void kernel_launch(void* const* d_in, const int* in_sizes, int n_in,
                              void* d_out, int out_size, void* d_ws, size_t ws_size,
                              hipStream_t stream) {
    const float* x         = (const float*)d_in[0];
    const float* context   = (const float*)d_in[1];
    const void*  mask      = d_in[2];
    const float* bias      = (const float*)d_in[3];
    const float* norm_g    = (const float*)d_in[4];
    const float* null_kv   = (const float*)d_in[5];
    const float* Wq        = (const float*)d_in[6];
    const float* Wkv       = (const float*)d_in[7];
    const float* ctx_ln_w  = (const float*)d_in[8];
    const float* ctx_ln_b  = (const float*)d_in[9];
    const float* Wctx      = (const float*)d_in[10];
    const float* bctx      = (const float*)d_in[11];
    const float* Wout      = (const float*)d_in[12];
    const float* out_gamma = (const float*)d_in[13];
    float* out = (float*)d_out;

    unsigned char* wsb = (unsigned char*)d_ws;
    unsigned short* xnb   = (unsigned short*)(wsb + 0);          //  8 MB bf16
    unsigned short* qbb   = (unsigned short*)(wsb + 8388608);    //  8 MB bf16
    float*          y     = (float*)(wsb + 0);                   // 16 MB f32 (overlays xnb+qbb, both dead)
    unsigned short* aoutp = (unsigned short*)(wsb + 16777216);   //  8 MB bf16
    unsigned short* KbP   = (unsigned short*)(wsb + 25165824);   // 2*Jp*64 bf16
    unsigned short* VtP   = (unsigned short*)(wsb + 25772032);   // 2*64*Jp bf16
    float*          maskf = (float*)(wsb + 26378240);            // 2*Jp f32
    unsigned short* WqT   = (unsigned short*)(wsb + 26397184);   // 2 MB
    unsigned short* WkvT  = (unsigned short*)(wsb + 28494336);   // 256 KB
    unsigned short* WoutT = (unsigned short*)(wsb + 28756480);   // 2 MB

    prep_all<<<3, 256, 0, stream>>>(mask, maskf, KbP, VtP, null_kv);
    ln1024<1><<<B * N, 256, 0, stream>>>(x, norm_g, xnb);
    // fold Dh^-0.5 * log2e into Wq so attention works in exp2 domain
    transpose_w<<<dim3(16, 16), 256, 0, stream>>>(Wq, WqT, 1024, 1024, 0.125f * LOG2E);
    transpose_w<<<dim3(16, 2), 256, 0, stream>>>(Wkv, WkvT, 1024, 128, 1.0f);
    transpose_w<<<dim3(16, 16), 256, 0, stream>>>(Wout, WoutT, 1024, 1024, 1.0f);
    ctx_proj<<<B * C, 128, 0, stream>>>(context, ctx_ln_w, ctx_ln_b, Wctx, bctx, KbP, VtP);
    // q = LN(x) @ (Wq*scale) -> bf16 (4096 x 1024)
    gemm_bf16<1><<<dim3(32, 8), 256, 0, stream>>>(xnb, WqT, nullptr, qbb, nullptr, nullptr, 4096, 1024, 1024);
    // k,v = LN(x) @ Wkv -> scatter bf16 into Kb rows / Vt cols 257..2304
    gemm_bf16<2><<<dim3(32, 1), 256, 0, stream>>>(xnb, WkvT, nullptr, nullptr, KbP, VtP, 4096, 128, 1024);
    attn_v14<<<dim3(16, 16), 1024, 0, stream>>>(qbb, KbP, VtP, bias, maskf, aoutp);
    // y = attn_out @ Wout -> f32
    gemm_bf16<0><<<dim3(32, 8), 256, 0, stream>>>(aoutp, WoutT, y, nullptr, nullptr, nullptr, 4096, 1024, 1024);
    ln1024<0><<<B * N, 256, 0, stream>>>(y, out_gamma, out);
}

// Round 15
// 239.656 us; speedup vs baseline: 3.2143x; 1.0986x over previous
//
#include <hip/hip_runtime.h>

// Problem constants
constexpr int B  = 2;
constexpr int N  = 2048;
constexpr int H  = 16;
constexpr int C  = 256;
constexpr int J  = C + 1 + N;    // 2305
constexpr int Jp = 2368;         // J padded to multiple of 64
constexpr int NT = Jp / 64;      // 37 j-tiles
constexpr float EPS = 1e-5f;
constexpr float LOG2E = 1.4426950408889634f;

typedef __bf16 bf16x8 __attribute__((ext_vector_type(8)));
typedef float  f32x4  __attribute__((ext_vector_type(4)));
typedef unsigned int uint4v __attribute__((ext_vector_type(4)));
typedef __attribute__((address_space(3))) unsigned int lds_u32;
typedef const __attribute__((address_space(1))) unsigned int glb_u32;

__device__ inline void load_lds16(const void* g, void* l) {
    __builtin_amdgcn_global_load_lds((glb_u32*)g, (lds_u32*)l, 16, 0, 0);
}
__device__ inline unsigned short f2bf(float f) {
    unsigned int u = __builtin_bit_cast(unsigned int, f);
    u += 0x7fffu + ((u >> 16) & 1u);
    return (unsigned short)(u >> 16);
}
__device__ inline float bf2f(unsigned short u) {
    return __builtin_bit_cast(float, (unsigned int)u << 16);
}
__device__ inline unsigned int packbf2(float a, float b) {
    union { __bf16 h[2]; unsigned int u; } cv;
    cv.h[0] = (__bf16)a;
    cv.h[1] = (__bf16)b;
    return cv.u;
}
__device__ inline float fexp2(float x) {
    float r;
    asm("v_exp_f32 %0, %1" : "=v"(r) : "v"(x));
    return r;
}
__device__ inline f32x4 mfma16(bf16x8 a, bf16x8 b, f32x4 c) {
    return __builtin_amdgcn_mfma_f32_16x16x32_bf16(a, b, c, 0, 0, 0);
}
// 16B load from a 4B-aligned pointer (J odd -> bias rows only dword-aligned).
__device__ inline f32x4 loadu4(const float* p) {
    f32x4 r;
    __builtin_memcpy(&r, p, 16);
    return r;
}

// ---------------------------------------------------------------------------
// Kernel 0: fused prep. Block 0: mask sniff -> additive maskf[b][Jp].
// Block 1: zero pads of Kb/Vt. Block 2: null token -> Kb row 256 / Vt col 256.
__global__ void prep_all(const void* __restrict__ mraw, float* __restrict__ maskf,
                         unsigned short* __restrict__ Kb, unsigned short* __restrict__ Vt,
                         const float* __restrict__ nkv) {
    const int t = threadIdx.x;
    if (blockIdx.x == 0) {
        __shared__ int bad_int, bad_f32;
        if (t == 0) { bad_int = 0; bad_f32 = 0; }
        __syncthreads();
        const unsigned int* w = (const unsigned int*)mraw;
        int li = 0, lf = 0;
        for (int i = t; i < 1152; i += 256) {
            unsigned int v = w[i];
            if (v > 1u) li = 1;
            if (v != 0u && v != 0x3F800000u) lf = 1;
        }
        if (li) atomicOr(&bad_int, 1);
        if (lf) atomicOr(&bad_f32, 1);
        __syncthreads();
        const int mode = (!bad_int) ? 0 : ((!bad_f32) ? 1 : 2);
        const unsigned char* bytes = (const unsigned char*)mraw;
        for (int i = t; i < 2 * Jp; i += 256) {
            const int b2 = i / Jp, jp = i - b2 * Jp;
            float v;
            if (jp == 0) v = 0.f;
            else if (jp >= J) v = -1e30f;
            else {
                const int idx = b2 * (C + N) + jp - 1;
                const int keep = (mode == 2) ? (bytes[idx] != 0) : (w[idx] != 0u);
                v = keep ? 0.f : -1e30f;
            }
            maskf[i] = v;
        }
    } else if (blockIdx.x == 1) {
        for (int i = t; i < 2 * 63 * 64; i += 256) {
            const int b2 = i / (63 * 64);
            const int rr = (i / 64) % 63;
            const int d  = i % 64;
            Kb[(size_t)(b2 * Jp + J + rr) * 64 + d] = 0;
        }
        for (int i = t; i < 2 * 64 * 63; i += 256) {
            const int b2 = i / (64 * 63);
            const int d  = (i / 63) % 64;
            const int cc = i % 63;
            Vt[(size_t)(b2 * 64 + d) * Jp + J + cc] = 0;
        }
    } else {
        if (t < 128) {
            const int b2 = t >> 6, d = t & 63;
            Kb[(size_t)(b2 * Jp + 256) * 64 + d] = f2bf(nkv[d]);
            Vt[(size_t)(b2 * 64 + d) * Jp + 256] = f2bf(nkv[64 + d]);
        }
    }
}

// ---------------------------------------------------------------------------
// Kernel 2: layernorm over 1024 (beta=0). BF16IN: input bf16 else f32;
// BF16OUT: write bf16 else f32.
template <int BF16IN, int BF16OUT>
__global__ void __launch_bounds__(256) ln1024(const void* __restrict__ xin,
                                              const float* __restrict__ gamma,
                                              void* __restrict__ outp) {
    const int row = blockIdx.x;
    const int t = threadIdx.x;
    float4 v;
    if (BF16IN) {
        const ushort4 u = *(const ushort4*)((const unsigned short*)xin + (size_t)row * 1024 + t * 4);
        v = make_float4(bf2f(u.x), bf2f(u.y), bf2f(u.z), bf2f(u.w));
    } else {
        v = ((const float4*)((const float*)xin + (size_t)row * 1024))[t];
    }
    float s  = v.x + v.y + v.z + v.w;
    float ss = v.x * v.x + v.y * v.y + v.z * v.z + v.w * v.w;
    #pragma unroll
    for (int o = 1; o < 64; o <<= 1) {
        s  += __shfl_xor(s, o);
        ss += __shfl_xor(ss, o);
    }
    __shared__ float red[8];
    const int w = t >> 6;
    if ((t & 63) == 0) { red[w * 2] = s; red[w * 2 + 1] = ss; }
    __syncthreads();
    s  = red[0] + red[2] + red[4] + red[6];
    ss = red[1] + red[3] + red[5] + red[7];
    const float mean = s * (1.0f / 1024.0f);
    const float var  = ss * (1.0f / 1024.0f) - mean * mean;
    const float rstd = rsqrtf(var + EPS);
    const float4 g = ((const float4*)gamma)[t];
    float o0 = (v.x - mean) * rstd * g.x;
    float o1 = (v.y - mean) * rstd * g.y;
    float o2 = (v.z - mean) * rstd * g.z;
    float o3 = (v.w - mean) * rstd * g.w;
    if (BF16OUT) {
        ushort4 u;
        u.x = f2bf(o0); u.y = f2bf(o1); u.z = f2bf(o2); u.w = f2bf(o3);
        *(ushort4*)((unsigned short*)outp + (size_t)row * 1024 + t * 4) = u;
    } else {
        *(float4*)((float*)outp + (size_t)row * 1024 + t * 4) = make_float4(o0, o1, o2, o3);
    }
}

// ---------------------------------------------------------------------------
// Kernel 3: fused weight transposes. Flat grid of 544 tiles:
//   [0,256):  Wq   1024x1024 -> WqT,   scale = 0.125*log2e
//   [256,288): Wkv 1024x128  -> WkvT,  scale = 1
//   [288,544): Wout 1024x1024 -> WoutT, scale = 1
__global__ void __launch_bounds__(256) transpose_all(
        const float* __restrict__ Wq, const float* __restrict__ Wkv,
        const float* __restrict__ Wout,
        unsigned short* __restrict__ WqT, unsigned short* __restrict__ WkvT,
        unsigned short* __restrict__ WoutT) {
    __shared__ float lds[64][68];
    const int id = blockIdx.x;
    const float* W;
    unsigned short* WT;
    int k0, n0, Nn;
    float scale;
    if (id < 256) {
        W = Wq;  WT = WqT;  Nn = 1024; scale = 0.125f * LOG2E;
        k0 = (id & 15) * 64; n0 = (id >> 4) * 64;
    } else if (id < 288) {
        W = Wkv; WT = WkvT; Nn = 128;  scale = 1.0f;
        k0 = ((id - 256) & 15) * 64; n0 = ((id - 256) >> 4) * 64;
    } else {
        W = Wout; WT = WoutT; Nn = 1024; scale = 1.0f;
        k0 = ((id - 288) & 15) * 64; n0 = ((id - 288) >> 4) * 64;
    }
    const int K = 1024;
    const int t = threadIdx.x;
    const int kk = t >> 4, nn = (t & 15) * 4;
    #pragma unroll
    for (int r = 0; r < 4; r++) {
        const float4 v = *(const float4*)(W + (size_t)(k0 + kk + r * 16) * Nn + n0 + nn);
        lds[kk + r * 16][nn + 0] = v.x;
        lds[kk + r * 16][nn + 1] = v.y;
        lds[kk + r * 16][nn + 2] = v.z;
        lds[kk + r * 16][nn + 3] = v.w;
    }
    __syncthreads();
    const int nr = t >> 2, kc = (t & 3) * 16;
    #pragma unroll
    for (int u4 = 0; u4 < 4; u4++) {
        ushort4 u;
        u.x = f2bf(lds[kc + u4 * 4 + 0][nr] * scale);
        u.y = f2bf(lds[kc + u4 * 4 + 1][nr] * scale);
        u.z = f2bf(lds[kc + u4 * 4 + 2][nr] * scale);
        u.w = f2bf(lds[kc + u4 * 4 + 3][nr] * scale);
        *(ushort4*)(WT + (size_t)(n0 + nr) * K + k0 + kc + u4 * 4) = u;
    }
}

// ---------------------------------------------------------------------------
// Kernel 4: context path: LN(context,512) @ Wctx + bctx -> Kb[0..255] / Vt cols.
__global__ void __launch_bounds__(128) ctx_proj(const float* __restrict__ ctx,
                                                const float* __restrict__ lw,
                                                const float* __restrict__ lb,
                                                const float* __restrict__ Wc,
                                                const float* __restrict__ bc,
                                                unsigned short* __restrict__ Kb,
                                                unsigned short* __restrict__ Vt) {
    const int row = blockIdx.x;          // 0..511
    const int b2 = row >> 8, ci = row & 255;
    const int t = threadIdx.x;           // 0..127
    __shared__ float cn[512];
    __shared__ float red[4];
    const float* xr = ctx + (size_t)row * 512;
    float4 v = ((const float4*)xr)[t];
    float s  = v.x + v.y + v.z + v.w;
    float ss = v.x * v.x + v.y * v.y + v.z * v.z + v.w * v.w;
    #pragma unroll
    for (int o = 1; o < 64; o <<= 1) {
        s  += __shfl_xor(s, o);
        ss += __shfl_xor(ss, o);
    }
    const int w = t >> 6;
    if ((t & 63) == 0) { red[w * 2] = s; red[w * 2 + 1] = ss; }
    __syncthreads();
    s  = red[0] + red[2];
    ss = red[1] + red[3];
    const float mean = s * (1.0f / 512.0f);
    const float var  = ss * (1.0f / 512.0f) - mean * mean;
    const float rstd = rsqrtf(var + EPS);
    const float4 g  = ((const float4*)lw)[t];
    const float4 be = ((const float4*)lb)[t];
    float4 c4;
    c4.x = (v.x - mean) * rstd * g.x + be.x;
    c4.y = (v.y - mean) * rstd * g.y + be.y;
    c4.z = (v.z - mean) * rstd * g.z + be.z;
    c4.w = (v.w - mean) * rstd * g.w + be.w;
    *(float4*)&cn[t * 4] = c4;
    __syncthreads();
    float acc = bc[t];
    #pragma unroll 8
    for (int d = 0; d < 512; d++) acc = fmaf(cn[d], Wc[d * 128 + t], acc);
    const unsigned short bv = f2bf(acc);
    if (t < 64) Kb[(size_t)(b2 * Jp + ci) * 64 + t] = bv;
    else        Vt[(size_t)(b2 * 64 + (t - 64)) * Jp + ci] = bv;
}

// ---------------------------------------------------------------------------
// Kernel 6: bf16 MFMA GEMM, 128x128 tile, BK=64, 4 waves, 2-phase dbuf.
// A (M,K) bf16 row-major; BT (Nn,K) bf16 row-major (= B^T).
// MODE 0: Cf f32 [M,Nn].  MODE 1: Cb bf16 [M,Nn].  MODE 2: kv scatter.
template <int MODE>
__global__ void __launch_bounds__(256, 2) gemm_bf16(
        const unsigned short* __restrict__ A, const unsigned short* __restrict__ BT,
        float* __restrict__ Cf, unsigned short* __restrict__ Cb,
        unsigned short* __restrict__ Kb, unsigned short* __restrict__ Vt,
        int M, int Nn, int K) {
    __shared__ __align__(16) unsigned char smem[65536];
    const int t = threadIdx.x;
    const int w = t >> 6, lane = t & 63;
    const int g = lane >> 4, ln15 = lane & 15;
    const int wm = w >> 1, wn = w & 1;
    const int row0 = blockIdx.x * 128, col0 = blockIdx.y * 128;
    const int nk = K >> 6;
    const int ls = lane >> 3;
    const int swz = (lane & 7) ^ ls;

    f32x4 acc[4][4];
    #pragma unroll
    for (int i = 0; i < 4; i++)
        #pragma unroll
        for (int jj = 0; jj < 4; jj++)
            acc[i][jj] = (f32x4){0.f, 0.f, 0.f, 0.f};

    auto stage = [&](int kt, int cur) {
        if (w < 2) {
            const unsigned short* src = A + (size_t)(row0 + w * 64 + ls) * K + kt * 64 + swz * 8;
            unsigned char* dst = smem + cur * 16384 + w * 8192;
            #pragma unroll
            for (int i = 0; i < 8; i++)
                load_lds16(src + (size_t)i * 8 * K, dst + i * 1024);
        } else {
            const unsigned short* src = BT + (size_t)(col0 + (w - 2) * 64 + ls) * K + kt * 64 + swz * 8;
            unsigned char* dst = smem + 32768 + cur * 16384 + (w - 2) * 8192;
            #pragma unroll
            for (int i = 0; i < 8; i++)
                load_lds16(src + (size_t)i * 8 * K, dst + i * 1024);
        }
    };

    stage(0, 0);
    __syncthreads();
    for (int kt = 0; kt < nk; kt++) {
        const int cur = kt & 1;
        if (kt + 1 < nk) stage(kt + 1, cur ^ 1);
        const unsigned char* As = smem + cur * 16384;
        const unsigned char* Bs = smem + 32768 + cur * 16384;
        #pragma unroll
        for (int ks = 0; ks < 2; ks++) {
            bf16x8 af[4], bf[4];
            #pragma unroll
            for (int mq = 0; mq < 4; mq++)
                af[mq] = *(const bf16x8*)(As + (wm * 64 + mq * 16 + ln15) * 128 +
                                          ((ks * 64 + g * 16) ^ ((ln15 & 7) << 4)));
            #pragma unroll
            for (int nq = 0; nq < 4; nq++)
                bf[nq] = *(const bf16x8*)(Bs + (wn * 64 + nq * 16 + ln15) * 128 +
                                          ((ks * 64 + g * 16) ^ ((ln15 & 7) << 4)));
            #pragma unroll
            for (int mq = 0; mq < 4; mq++)
                #pragma unroll
                for (int nq = 0; nq < 4; nq++)
                    acc[mq][nq] = mfma16(af[mq], bf[nq], acc[mq][nq]);
        }
        __syncthreads();
    }

    #pragma unroll
    for (int mq = 0; mq < 4; mq++) {
        #pragma unroll
        for (int nq = 0; nq < 4; nq++) {
            #pragma unroll
            for (int r = 0; r < 4; r++) {
                const int gr = row0 + wm * 64 + mq * 16 + g * 4 + r;
                const int gc = col0 + wn * 64 + nq * 16 + ln15;
                if (MODE == 0) {
                    Cf[(size_t)gr * Nn + gc] = acc[mq][nq][r];
                } else if (MODE == 1) {
                    Cb[(size_t)gr * Nn + gc] = f2bf(acc[mq][nq][r]);
                } else {
                    const int b2 = gr >> 11, tok = gr & 2047;
                    const unsigned short v = f2bf(acc[mq][nq][r]);
                    if (gc < 64) Kb[(size_t)(b2 * Jp + 257 + tok) * 64 + gc] = v;
                    else         Vt[(size_t)(b2 * 64 + gc - 64) * Jp + 257 + tok] = v;
                }
            }
        }
    }
}

// ---------------------------------------------------------------------------
// Kernel 7: flash attention v8 (measured best, restored verbatim). Grid
// (16,16): one 1024-thread block per CU, 128 q-rows x both batches. Per
// j-tile the CU stages ONCE: K/V (32 KB, global_load_lds, swizzled src) and
// the bias tile (32 KB f32, coalesced loads -> regs -> padded LDS [128][68]),
// both DOUBLE-buffered (bias regs prefetched one tile ahead; HBM latency
// hides under compute). Waves (b2 = w&1, wq = w>>1) compute independently
// between barriers; one barrier per tile. LDS 132 KB -> 1 block/CU.
__global__ void __launch_bounds__(1024, 4) attn_v8(
        const unsigned short* __restrict__ qb, const unsigned short* __restrict__ Kb,
        const unsigned short* __restrict__ Vt, const float* __restrict__ bias,
        const float* __restrict__ maskf, unsigned short* __restrict__ aout) {
    __shared__ __align__(16) unsigned char smem[135168];   // 64K kv dbuf + 68K bias dbuf
    const int t = threadIdx.x;
    const int w = t >> 6, lane = t & 63;
    const int g = lane >> 4, ln15 = lane & 15;
    const int i0 = blockIdx.x * 128, h = blockIdx.y;
    const int b2 = w & 1, wq = w >> 1;            // wave: batch b2, q-rows i0+wq*16..+15
    const int ls = lane >> 3;
    const int swz = (lane & 7) ^ ls;

    // ---- K/V staging: 16 waves x 2 KB. Waves 0..7 stage K (kb = w>>2,
    // quarter = w&3 -> 16 j-rows), waves 8..15 stage V (d-rows).
    auto stage = [&](int jt, int cur) {
        const int j0 = jt * 64;
        const int quarter = w & 3;
        if (w < 8) {
            const int kb = (w >> 2) & 1;
            const unsigned short* src = Kb + (size_t)(kb * Jp + j0 + quarter * 16 + ls) * 64 + swz * 8;
            unsigned char* dst = smem + cur * 32768 + kb * 8192 + quarter * 2048;
            load_lds16(src, dst);
            load_lds16(src + (size_t)8 * 64, dst + 1024);
        } else {
            const int vb = (w >> 2) & 1;
            const unsigned short* src = Vt + (size_t)(vb * 64 + quarter * 16 + ls) * Jp + j0 + swz * 8;
            unsigned char* dst = smem + cur * 32768 + 16384 + vb * 8192 + quarter * 2048;
            load_lds16(src, dst);
            load_lds16(src + (size_t)8 * Jp, dst + 1024);
        }
    };

    // ---- Bias staging: [128 q][64 j] f32 -> LDS [128][68] (padded).
    const int bq  = t >> 3;          // 0..127: q-row this thread stages
    const int bs0 = t & 7;           // 16B slot (pass 0); pass 1 = +8
    const float* biasQrow = bias + ((size_t)h * N + i0 + bq) * J;
    auto bias_issue = [&](int jt, f32x4& r0, f32x4& r1) {
        const int j0 = jt * 64;
        if (j0 + 64 <= J) {
            r0 = loadu4(biasQrow + j0 + bs0 * 4);
            r1 = loadu4(biasQrow + j0 + (bs0 + 8) * 4);
        } else {
            #pragma unroll
            for (int c = 0; c < 4; c++) {
                const int jA = j0 + bs0 * 4 + c;
                const int jB = j0 + (bs0 + 8) * 4 + c;
                r0[c] = (jA < J) ? biasQrow[jA] : 0.f;
                r1[c] = (jB < J) ? biasQrow[jB] : 0.f;
            }
        }
    };
    auto bias_write = [&](int cur, const f32x4& r0, const f32x4& r1) {
        float* basep = (float*)(smem + 65536 + cur * 34816) + bq * 68;
        *(f32x4*)(basep + bs0 * 4) = r0;
        *(f32x4*)(basep + (bs0 + 8) * 4) = r1;
    };

    // Q fragments (B-operand of swapped QK^T): q-row = ln15, d k-contig.
    bf16x8 qf[2];
    #pragma unroll
    for (int ks = 0; ks < 2; ks++)
        qf[ks] = *(const bf16x8*)(qb + (size_t)(b2 * N + i0 + wq * 16 + ln15) * 1024 +
                                  h * 64 + ks * 32 + g * 8);

    float mrun = -1e30f, lrun = 0.f;
    f32x4 outA[4];
    #pragma unroll
    for (int nq = 0; nq < 4; nq++) outA[nq] = (f32x4){0.f, 0.f, 0.f, 0.f};

    const int srclA = ln15 + (((2 * g + 0) & 3) << 4);
    const int srclB = ln15 + (((2 * g + 1) & 3) << 4);

    auto compute = [&](int jt, int cur) {
        const int j0 = jt * 64;
        const unsigned char* Kl = smem + cur * 32768 + b2 * 8192;
        const unsigned char* Vl = smem + cur * 32768 + 16384 + b2 * 8192;
        const float* bb = (const float*)(smem + 65536 + cur * 34816) + (wq * 16 + ln15) * 68;

        f32x4 mk[4];
        #pragma unroll
        for (int jqm = 0; jqm < 4; jqm++)
            mk[jqm] = *(const f32x4*)(maskf + b2 * Jp + j0 + jqm * 16 + g * 4);
        f32x4 br[4];
        #pragma unroll
        for (int jqm = 0; jqm < 4; jqm++)
            br[jqm] = *(const f32x4*)(bb + (jqm * 4 + g) * 4);

        // S^T = K . Q : frag jqm rows j = j0+jqm*16+g*4+r, col q = ln15
        f32x4 S[4];
        #pragma unroll
        for (int jqm = 0; jqm < 4; jqm++) S[jqm] = (f32x4){0.f, 0.f, 0.f, 0.f};
        #pragma unroll
        for (int ks = 0; ks < 2; ks++) {
            bf16x8 ka[4];
            #pragma unroll
            for (int jqm = 0; jqm < 4; jqm++)
                ka[jqm] = *(const bf16x8*)(Kl + (jqm * 16 + ln15) * 128 +
                                           ((ks * 64 + g * 16) ^ ((ln15 & 7) << 4)));
            __builtin_amdgcn_s_setprio(1);
            #pragma unroll
            for (int jqm = 0; jqm < 4; jqm++)
                S[jqm] = mfma16(ka[jqm], qf[ks], S[jqm]);
            __builtin_amdgcn_s_setprio(0);
        }

        // log2 domain: S pre-scaled by log2e (via Wq), bias*log2e via fma
        float sv[4][4];
        #pragma unroll
        for (int jqm = 0; jqm < 4; jqm++)
            #pragma unroll
            for (int r = 0; r < 4; r++)
                sv[jqm][r] = fmaf(br[jqm][r], LOG2E, S[jqm][r]) + mk[jqm][r];

        float tmj[4];
        #pragma unroll
        for (int jqm = 0; jqm < 4; jqm++)
            tmj[jqm] = fmaxf(fmaxf(sv[jqm][0], sv[jqm][1]), fmaxf(sv[jqm][2], sv[jqm][3]));
        float tm = fmaxf(fmaxf(tmj[0], tmj[1]), fmaxf(tmj[2], tmj[3]));
        tm = fmaxf(tm, __shfl_xor(tm, 16));
        tm = fmaxf(tm, __shfl_xor(tm, 32));

        if (!__all(tm <= mrun)) {      // exact skip: rescale only if max grew
            const float mnew = fmaxf(mrun, tm);
            const float cor = fexp2(mrun - mnew);
            mrun = mnew;
            float corr[4];
            #pragma unroll
            for (int r = 0; r < 4; r++) corr[r] = __shfl(cor, g * 4 + r, 64);
            #pragma unroll
            for (int nq = 0; nq < 4; nq++)
                #pragma unroll
                for (int r = 0; r < 4; r++)
                    outA[nq][r] *= corr[r];
            lrun *= cor;
        }
        const float mcur = mrun;

        float p[4][4];
        #pragma unroll
        for (int jqm = 0; jqm < 4; jqm++)
            #pragma unroll
            for (int r = 0; r < 4; r++)
                p[jqm][r] = fexp2(sv[jqm][r] - mcur);
        float tsj[4];
        #pragma unroll
        for (int jqm = 0; jqm < 4; jqm++)
            tsj[jqm] = (p[jqm][0] + p[jqm][1]) + (p[jqm][2] + p[jqm][3]);
        float ts = (tsj[0] + tsj[1]) + (tsj[2] + tsj[3]);
        ts += __shfl_xor(ts, 16);
        ts += __shfl_xor(ts, 32);
        lrun += ts;

        unsigned int Wp[4][2];
        #pragma unroll
        for (int jqm = 0; jqm < 4; jqm++) {
            Wp[jqm][0] = packbf2(p[jqm][0], p[jqm][1]);
            Wp[jqm][1] = packbf2(p[jqm][2], p[jqm][3]);
        }

        // repack to PV A-fragments: lane needs P[q=ln15][j=ks*32+g*8+0..7]
        #pragma unroll
        for (int ks = 0; ks < 2; ks++) {
            uint4v wd;
            #pragma unroll
            for (int widx = 0; widx < 4; widx++) {
                const int srcl = (widx >> 1) ? srclB : srclA;
                const int t0 = __shfl((int)Wp[ks * 2 + 0][widx & 1], srcl, 64);
                const int t1 = __shfl((int)Wp[ks * 2 + 1][widx & 1], srcl, 64);
                wd[widx] = (unsigned int)((g >> 1) ? t1 : t0);
            }
            const bf16x8 pa = __builtin_bit_cast(bf16x8, wd);
            bf16x8 vf[4];
            #pragma unroll
            for (int nq = 0; nq < 4; nq++)
                vf[nq] = *(const bf16x8*)(Vl + (nq * 16 + ln15) * 128 +
                                          ((ks * 64 + g * 16) ^ ((ln15 & 7) << 4)));
            __builtin_amdgcn_s_setprio(1);
            #pragma unroll
            for (int nq = 0; nq < 4; nq++)
                outA[nq] = mfma16(pa, vf[nq], outA[nq]);
            __builtin_amdgcn_s_setprio(0);
        }
    };

    // ---- pipeline: bias regs in flight during compute; all LDS dbuf'd.
    f32x4 bR0, bR1;
    bias_issue(0, bR0, bR1);
    stage(0, 0);
    bias_write(0, bR0, bR1);       // compiler inserts counted vmcnt wait for bR
    __syncthreads();
    for (int jt = 0; jt < NT; jt++) {
        const int cur = jt & 1;
        if (jt + 1 < NT) {
            bias_issue(jt + 1, bR0, bR1);   // HBM latency hides under compute
            stage(jt + 1, cur ^ 1);
        }
        compute(jt, cur);
        if (jt + 1 < NT) bias_write(cur ^ 1, bR0, bR1);
        __syncthreads();
    }

    const float inv = 1.0f / lrun;
    float invr[4];
    #pragma unroll
    for (int r = 0; r < 4; r++) invr[r] = __shfl(inv, g * 4 + r, 64);
    #pragma unroll
    for (int nq = 0; nq < 4; nq++)
        #pragma unroll
        for (int r = 0; r < 4; r++)
            aout[(size_t)(b2 * N + i0 + wq * 16 + g * 4 + r) * 1024 +
                 h * 64 + nq * 16 + ln15] = f2bf(outA[nq][r] * invr[r]);
}

// ---------------------------------------------------------------------------
extern "C" void kernel_launch(void* const* d_in, const int* in_sizes, int n_in,
                              void* d_out, int out_size, void* d_ws, size_t ws_size,
                              hipStream_t stream) {
    const float* x         = (const float*)d_in[0];
    const float* context   = (const float*)d_in[1];
    const void*  mask      = d_in[2];
    const float* bias      = (const float*)d_in[3];
    const float* norm_g    = (const float*)d_in[4];
    const float* null_kv   = (const float*)d_in[5];
    const float* Wq        = (const float*)d_in[6];
    const float* Wkv       = (const float*)d_in[7];
    const float* ctx_ln_w  = (const float*)d_in[8];
    const float* ctx_ln_b  = (const float*)d_in[9];
    const float* Wctx      = (const float*)d_in[10];
    const float* bctx      = (const float*)d_in[11];
    const float* Wout      = (const float*)d_in[12];
    const float* out_gamma = (const float*)d_in[13];
    float* out = (float*)d_out;

    unsigned char* wsb = (unsigned char*)d_ws;
    unsigned short* xnb   = (unsigned short*)(wsb + 0);          //  8 MB bf16
    unsigned short* qbb   = (unsigned short*)(wsb + 8388608);    //  8 MB bf16
    unsigned short* yb    = qbb;                                 //  8 MB bf16 (qbb dead after attn)
    unsigned short* aoutp = (unsigned short*)(wsb + 16777216);   //  8 MB bf16
    unsigned short* KbP   = (unsigned short*)(wsb + 25165824);   // 2*Jp*64 bf16
    unsigned short* VtP   = (unsigned short*)(wsb + 25772032);   // 2*64*Jp bf16
    float*          maskf = (float*)(wsb + 26378240);            // 2*Jp f32
    unsigned short* WqT   = (unsigned short*)(wsb + 26397184);   // 2 MB
    unsigned short* WkvT  = (unsigned short*)(wsb + 28494336);   // 256 KB
    unsigned short* WoutT = (unsigned short*)(wsb + 28756480);   // 2 MB

    prep_all<<<3, 256, 0, stream>>>(mask, maskf, KbP, VtP, null_kv);
    ln1024<0, 1><<<B * N, 256, 0, stream>>>(x, norm_g, xnb);
    transpose_all<<<544, 256, 0, stream>>>(Wq, Wkv, Wout, WqT, WkvT, WoutT);
    ctx_proj<<<B * C, 128, 0, stream>>>(context, ctx_ln_w, ctx_ln_b, Wctx, bctx, KbP, VtP);
    // q = LN(x) @ (Wq * 0.125*log2e) -> bf16 (4096 x 1024)
    gemm_bf16<1><<<dim3(32, 8), 256, 0, stream>>>(xnb, WqT, nullptr, qbb, nullptr, nullptr, 4096, 1024, 1024);
    // k,v = LN(x) @ Wkv -> scatter bf16 into Kb rows / Vt cols 257..2304
    gemm_bf16<2><<<dim3(32, 1), 256, 0, stream>>>(xnb, WkvT, nullptr, nullptr, KbP, VtP, 4096, 128, 1024);
    attn_v8<<<dim3(16, 16), 1024, 0, stream>>>(qbb, KbP, VtP, bias, maskf, aoutp);
    // y = attn_out @ Wout -> bf16 (overwrites qbb region; qbb consumed above)
    gemm_bf16<1><<<dim3(32, 8), 256, 0, stream>>>(aoutp, WoutT, nullptr, yb, nullptr, nullptr, 4096, 1024, 1024);
    ln1024<1, 0><<<B * N, 256, 0, stream>>>(yb, out_gamma, out);
}

// Round 16
// 225.632 us; speedup vs baseline: 3.4141x; 1.0622x over previous
//
#include <hip/hip_runtime.h>

// Problem constants
constexpr int B  = 2;
constexpr int N  = 2048;
constexpr int H  = 16;
constexpr int C  = 256;
constexpr int J  = C + 1 + N;    // 2305
constexpr int Jp = 2368;         // J padded to multiple of 64
constexpr int NT = Jp / 64;      // 37 j-tiles
constexpr float EPS = 1e-5f;
constexpr float LOG2E = 1.4426950408889634f;

typedef __bf16 bf16x8 __attribute__((ext_vector_type(8)));
typedef float  f32x4  __attribute__((ext_vector_type(4)));
typedef unsigned int uint4v __attribute__((ext_vector_type(4)));
typedef __attribute__((address_space(3))) unsigned int lds_u32;
typedef const __attribute__((address_space(1))) unsigned int glb_u32;

__device__ inline void load_lds16(const void* g, void* l) {
    __builtin_amdgcn_global_load_lds((glb_u32*)g, (lds_u32*)l, 16, 0, 0);
}
__device__ inline unsigned short f2bf(float f) {
    unsigned int u = __builtin_bit_cast(unsigned int, f);
    u += 0x7fffu + ((u >> 16) & 1u);
    return (unsigned short)(u >> 16);
}
__device__ inline float bf2f(unsigned short u) {
    return __builtin_bit_cast(float, (unsigned int)u << 16);
}
__device__ inline unsigned int packbf2(float a, float b) {
    union { __bf16 h[2]; unsigned int u; } cv;
    cv.h[0] = (__bf16)a;
    cv.h[1] = (__bf16)b;
    return cv.u;
}
__device__ inline float fexp2(float x) {
    float r;
    asm("v_exp_f32 %0, %1" : "=v"(r) : "v"(x));
    return r;
}
__device__ inline f32x4 mfma16(bf16x8 a, bf16x8 b, f32x4 c) {
    return __builtin_amdgcn_mfma_f32_16x16x32_bf16(a, b, c, 0, 0, 0);
}
// 16B load from a 4B-aligned pointer (J odd -> bias rows only dword-aligned).
__device__ inline f32x4 loadu4(const float* p) {
    f32x4 r;
    __builtin_memcpy(&r, p, 16);
    return r;
}

// ---------------------------------------------------------------------------
// Kernel 0: fused setup. Flat grid of 547 blocks:
//   [0,256):   transpose Wq   (scale 0.125*log2e) -> WqT
//   [256,288): transpose Wkv  -> WkvT
//   [288,544): transpose Wout -> WoutT
//   544: mask sniff -> maskf; 545: zero pads; 546: null token fill.
__global__ void __launch_bounds__(256) setup_all(
        const float* __restrict__ Wq, const float* __restrict__ Wkv,
        const float* __restrict__ Wout,
        unsigned short* __restrict__ WqT, unsigned short* __restrict__ WkvT,
        unsigned short* __restrict__ WoutT,
        const void* __restrict__ mraw, float* __restrict__ maskf,
        unsigned short* __restrict__ Kb, unsigned short* __restrict__ Vt,
        const float* __restrict__ nkv) {
    const int id = blockIdx.x;
    const int t = threadIdx.x;
    if (id < 544) {
        __shared__ float lds[64][68];
        const float* W;
        unsigned short* WT;
        int k0, n0, Nn;
        float scale;
        if (id < 256) {
            W = Wq;  WT = WqT;  Nn = 1024; scale = 0.125f * LOG2E;
            k0 = (id & 15) * 64; n0 = (id >> 4) * 64;
        } else if (id < 288) {
            W = Wkv; WT = WkvT; Nn = 128;  scale = 1.0f;
            k0 = ((id - 256) & 15) * 64; n0 = ((id - 256) >> 4) * 64;
        } else {
            W = Wout; WT = WoutT; Nn = 1024; scale = 1.0f;
            k0 = ((id - 288) & 15) * 64; n0 = ((id - 288) >> 4) * 64;
        }
        const int K = 1024;
        const int kk = t >> 4, nn = (t & 15) * 4;
        #pragma unroll
        for (int r = 0; r < 4; r++) {
            const float4 v = *(const float4*)(W + (size_t)(k0 + kk + r * 16) * Nn + n0 + nn);
            lds[kk + r * 16][nn + 0] = v.x;
            lds[kk + r * 16][nn + 1] = v.y;
            lds[kk + r * 16][nn + 2] = v.z;
            lds[kk + r * 16][nn + 3] = v.w;
        }
        __syncthreads();
        const int nr = t >> 2, kc = (t & 3) * 16;
        #pragma unroll
        for (int u4 = 0; u4 < 4; u4++) {
            ushort4 u;
            u.x = f2bf(lds[kc + u4 * 4 + 0][nr] * scale);
            u.y = f2bf(lds[kc + u4 * 4 + 1][nr] * scale);
            u.z = f2bf(lds[kc + u4 * 4 + 2][nr] * scale);
            u.w = f2bf(lds[kc + u4 * 4 + 3][nr] * scale);
            *(ushort4*)(WT + (size_t)(n0 + nr) * K + k0 + kc + u4 * 4) = u;
        }
    } else if (id == 544) {
        __shared__ int bad_int, bad_f32;
        if (t == 0) { bad_int = 0; bad_f32 = 0; }
        __syncthreads();
        const unsigned int* w = (const unsigned int*)mraw;
        int li = 0, lf = 0;
        for (int i = t; i < 1152; i += 256) {
            unsigned int v = w[i];
            if (v > 1u) li = 1;
            if (v != 0u && v != 0x3F800000u) lf = 1;
        }
        if (li) atomicOr(&bad_int, 1);
        if (lf) atomicOr(&bad_f32, 1);
        __syncthreads();
        const int mode = (!bad_int) ? 0 : ((!bad_f32) ? 1 : 2);
        const unsigned char* bytes = (const unsigned char*)mraw;
        for (int i = t; i < 2 * Jp; i += 256) {
            const int b2 = i / Jp, jp = i - b2 * Jp;
            float v;
            if (jp == 0) v = 0.f;
            else if (jp >= J) v = -1e30f;
            else {
                const int idx = b2 * (C + N) + jp - 1;
                const int keep = (mode == 2) ? (bytes[idx] != 0) : (w[idx] != 0u);
                v = keep ? 0.f : -1e30f;
            }
            maskf[i] = v;
        }
    } else if (id == 545) {
        for (int i = t; i < 2 * 63 * 64; i += 256) {
            const int b2 = i / (63 * 64);
            const int rr = (i / 64) % 63;
            const int d  = i % 64;
            Kb[(size_t)(b2 * Jp + J + rr) * 64 + d] = 0;
        }
        for (int i = t; i < 2 * 64 * 63; i += 256) {
            const int b2 = i / (64 * 63);
            const int d  = (i / 63) % 64;
            const int cc = i % 63;
            Vt[(size_t)(b2 * 64 + d) * Jp + J + cc] = 0;
        }
    } else {
        if (t < 128) {
            const int b2 = t >> 6, d = t & 63;
            Kb[(size_t)(b2 * Jp + 256) * 64 + d] = f2bf(nkv[d]);
            Vt[(size_t)(b2 * 64 + d) * Jp + 256] = f2bf(nkv[64 + d]);
        }
    }
}

// ---------------------------------------------------------------------------
// Kernel 2: layernorm over 1024 (beta=0). BF16IN / BF16OUT select dtypes.
template <int BF16IN, int BF16OUT>
__global__ void __launch_bounds__(256) ln1024(const void* __restrict__ xin,
                                              const float* __restrict__ gamma,
                                              void* __restrict__ outp) {
    const int row = blockIdx.x;
    const int t = threadIdx.x;
    float4 v;
    if (BF16IN) {
        const ushort4 u = *(const ushort4*)((const unsigned short*)xin + (size_t)row * 1024 + t * 4);
        v = make_float4(bf2f(u.x), bf2f(u.y), bf2f(u.z), bf2f(u.w));
    } else {
        v = ((const float4*)((const float*)xin + (size_t)row * 1024))[t];
    }
    float s  = v.x + v.y + v.z + v.w;
    float ss = v.x * v.x + v.y * v.y + v.z * v.z + v.w * v.w;
    #pragma unroll
    for (int o = 1; o < 64; o <<= 1) {
        s  += __shfl_xor(s, o);
        ss += __shfl_xor(ss, o);
    }
    __shared__ float red[8];
    const int w = t >> 6;
    if ((t & 63) == 0) { red[w * 2] = s; red[w * 2 + 1] = ss; }
    __syncthreads();
    s  = red[0] + red[2] + red[4] + red[6];
    ss = red[1] + red[3] + red[5] + red[7];
    const float mean = s * (1.0f / 1024.0f);
    const float var  = ss * (1.0f / 1024.0f) - mean * mean;
    const float rstd = rsqrtf(var + EPS);
    const float4 g = ((const float4*)gamma)[t];
    float o0 = (v.x - mean) * rstd * g.x;
    float o1 = (v.y - mean) * rstd * g.y;
    float o2 = (v.z - mean) * rstd * g.z;
    float o3 = (v.w - mean) * rstd * g.w;
    if (BF16OUT) {
        ushort4 u;
        u.x = f2bf(o0); u.y = f2bf(o1); u.z = f2bf(o2); u.w = f2bf(o3);
        *(ushort4*)((unsigned short*)outp + (size_t)row * 1024 + t * 4) = u;
    } else {
        *(float4*)((float*)outp + (size_t)row * 1024 + t * 4) = make_float4(o0, o1, o2, o3);
    }
}

// ---------------------------------------------------------------------------
// Kernel 4: context path: LN(context,512) @ Wctx + bctx -> Kb[0..255] / Vt cols.
__global__ void __launch_bounds__(128) ctx_proj(const float* __restrict__ ctx,
                                                const float* __restrict__ lw,
                                                const float* __restrict__ lb,
                                                const float* __restrict__ Wc,
                                                const float* __restrict__ bc,
                                                unsigned short* __restrict__ Kb,
                                                unsigned short* __restrict__ Vt) {
    const int row = blockIdx.x;          // 0..511
    const int b2 = row >> 8, ci = row & 255;
    const int t = threadIdx.x;           // 0..127
    __shared__ float cn[512];
    __shared__ float red[4];
    const float* xr = ctx + (size_t)row * 512;
    float4 v = ((const float4*)xr)[t];
    float s  = v.x + v.y + v.z + v.w;
    float ss = v.x * v.x + v.y * v.y + v.z * v.z + v.w * v.w;
    #pragma unroll
    for (int o = 1; o < 64; o <<= 1) {
        s  += __shfl_xor(s, o);
        ss += __shfl_xor(ss, o);
    }
    const int w = t >> 6;
    if ((t & 63) == 0) { red[w * 2] = s; red[w * 2 + 1] = ss; }
    __syncthreads();
    s  = red[0] + red[2];
    ss = red[1] + red[3];
    const float mean = s * (1.0f / 512.0f);
    const float var  = ss * (1.0f / 512.0f) - mean * mean;
    const float rstd = rsqrtf(var + EPS);
    const float4 g  = ((const float4*)lw)[t];
    const float4 be = ((const float4*)lb)[t];
    float4 c4;
    c4.x = (v.x - mean) * rstd * g.x + be.x;
    c4.y = (v.y - mean) * rstd * g.y + be.y;
    c4.z = (v.z - mean) * rstd * g.z + be.z;
    c4.w = (v.w - mean) * rstd * g.w + be.w;
    *(float4*)&cn[t * 4] = c4;
    __syncthreads();
    float acc = bc[t];
    #pragma unroll 8
    for (int d = 0; d < 512; d++) acc = fmaf(cn[d], Wc[d * 128 + t], acc);
    const unsigned short bv = f2bf(acc);
    if (t < 64) Kb[(size_t)(b2 * Jp + ci) * 64 + t] = bv;
    else        Vt[(size_t)(b2 * 64 + (t - 64)) * Jp + ci] = bv;
}

// ---------------------------------------------------------------------------
// Kernel 5: merged projection GEMM. Grid (32, 9): y<8 -> q tile (WqT, col0 =
// y*128, write qbb bf16); y==8 -> kv tile (WkvT, 128 cols, scatter to Kb/Vt).
// 128x128 tile, BK=64, 4 waves, 2-phase dbuf (identical inner loop).
__global__ void __launch_bounds__(256, 2) proj_gemm(
        const unsigned short* __restrict__ A, const unsigned short* __restrict__ WqT,
        const unsigned short* __restrict__ WkvT, unsigned short* __restrict__ qbb,
        unsigned short* __restrict__ Kb, unsigned short* __restrict__ Vt) {
    __shared__ __align__(16) unsigned char smem[65536];
    const int K = 1024;
    const int isKV = (blockIdx.y == 8);
    const unsigned short* BT = isKV ? WkvT : WqT;
    const int t = threadIdx.x;
    const int w = t >> 6, lane = t & 63;
    const int g = lane >> 4, ln15 = lane & 15;
    const int wm = w >> 1, wn = w & 1;
    const int row0 = blockIdx.x * 128;
    const int col0 = isKV ? 0 : blockIdx.y * 128;
    const int ls = lane >> 3;
    const int swz = (lane & 7) ^ ls;

    f32x4 acc[4][4];
    #pragma unroll
    for (int i = 0; i < 4; i++)
        #pragma unroll
        for (int jj = 0; jj < 4; jj++)
            acc[i][jj] = (f32x4){0.f, 0.f, 0.f, 0.f};

    auto stage = [&](int kt, int cur) {
        if (w < 2) {
            const unsigned short* src = A + (size_t)(row0 + w * 64 + ls) * K + kt * 64 + swz * 8;
            unsigned char* dst = smem + cur * 16384 + w * 8192;
            #pragma unroll
            for (int i = 0; i < 8; i++)
                load_lds16(src + (size_t)i * 8 * K, dst + i * 1024);
        } else {
            const unsigned short* src = BT + (size_t)(col0 + (w - 2) * 64 + ls) * K + kt * 64 + swz * 8;
            unsigned char* dst = smem + 32768 + cur * 16384 + (w - 2) * 8192;
            #pragma unroll
            for (int i = 0; i < 8; i++)
                load_lds16(src + (size_t)i * 8 * K, dst + i * 1024);
        }
    };

    stage(0, 0);
    __syncthreads();
    for (int kt = 0; kt < 16; kt++) {
        const int cur = kt & 1;
        if (kt + 1 < 16) stage(kt + 1, cur ^ 1);
        const unsigned char* As = smem + cur * 16384;
        const unsigned char* Bs = smem + 32768 + cur * 16384;
        #pragma unroll
        for (int ks = 0; ks < 2; ks++) {
            bf16x8 af[4], bf[4];
            #pragma unroll
            for (int mq = 0; mq < 4; mq++)
                af[mq] = *(const bf16x8*)(As + (wm * 64 + mq * 16 + ln15) * 128 +
                                          ((ks * 64 + g * 16) ^ ((ln15 & 7) << 4)));
            #pragma unroll
            for (int nq = 0; nq < 4; nq++)
                bf[nq] = *(const bf16x8*)(Bs + (wn * 64 + nq * 16 + ln15) * 128 +
                                          ((ks * 64 + g * 16) ^ ((ln15 & 7) << 4)));
            #pragma unroll
            for (int mq = 0; mq < 4; mq++)
                #pragma unroll
                for (int nq = 0; nq < 4; nq++)
                    acc[mq][nq] = mfma16(af[mq], bf[nq], acc[mq][nq]);
        }
        __syncthreads();
    }

    #pragma unroll
    for (int mq = 0; mq < 4; mq++) {
        #pragma unroll
        for (int nq = 0; nq < 4; nq++) {
            #pragma unroll
            for (int r = 0; r < 4; r++) {
                const int gr = row0 + wm * 64 + mq * 16 + g * 4 + r;
                const int gc = col0 + wn * 64 + nq * 16 + ln15;
                const unsigned short v = f2bf(acc[mq][nq][r]);
                if (!isKV) {
                    qbb[(size_t)gr * 1024 + gc] = v;
                } else {
                    const int b2 = gr >> 11, tok = gr & 2047;
                    if (gc < 64) Kb[(size_t)(b2 * Jp + 257 + tok) * 64 + gc] = v;
                    else         Vt[(size_t)(b2 * 64 + gc - 64) * Jp + 257 + tok] = v;
                }
            }
        }
    }
}

// ---------------------------------------------------------------------------
// Kernel 6: bf16 MFMA GEMM (out-projection), 128x128 tile, BK=64, 2-phase dbuf.
// A (M,K) bf16 row-major; BT (Nn,K) bf16 row-major. Writes bf16.
__global__ void __launch_bounds__(256, 2) gemm_out(
        const unsigned short* __restrict__ A, const unsigned short* __restrict__ BT,
        unsigned short* __restrict__ Cb) {
    __shared__ __align__(16) unsigned char smem[65536];
    const int K = 1024;
    const int t = threadIdx.x;
    const int w = t >> 6, lane = t & 63;
    const int g = lane >> 4, ln15 = lane & 15;
    const int wm = w >> 1, wn = w & 1;
    const int row0 = blockIdx.x * 128, col0 = blockIdx.y * 128;
    const int ls = lane >> 3;
    const int swz = (lane & 7) ^ ls;

    f32x4 acc[4][4];
    #pragma unroll
    for (int i = 0; i < 4; i++)
        #pragma unroll
        for (int jj = 0; jj < 4; jj++)
            acc[i][jj] = (f32x4){0.f, 0.f, 0.f, 0.f};

    auto stage = [&](int kt, int cur) {
        if (w < 2) {
            const unsigned short* src = A + (size_t)(row0 + w * 64 + ls) * K + kt * 64 + swz * 8;
            unsigned char* dst = smem + cur * 16384 + w * 8192;
            #pragma unroll
            for (int i = 0; i < 8; i++)
                load_lds16(src + (size_t)i * 8 * K, dst + i * 1024);
        } else {
            const unsigned short* src = BT + (size_t)(col0 + (w - 2) * 64 + ls) * K + kt * 64 + swz * 8;
            unsigned char* dst = smem + 32768 + cur * 16384 + (w - 2) * 8192;
            #pragma unroll
            for (int i = 0; i < 8; i++)
                load_lds16(src + (size_t)i * 8 * K, dst + i * 1024);
        }
    };

    stage(0, 0);
    __syncthreads();
    for (int kt = 0; kt < 16; kt++) {
        const int cur = kt & 1;
        if (kt + 1 < 16) stage(kt + 1, cur ^ 1);
        const unsigned char* As = smem + cur * 16384;
        const unsigned char* Bs = smem + 32768 + cur * 16384;
        #pragma unroll
        for (int ks = 0; ks < 2; ks++) {
            bf16x8 af[4], bf[4];
            #pragma unroll
            for (int mq = 0; mq < 4; mq++)
                af[mq] = *(const bf16x8*)(As + (wm * 64 + mq * 16 + ln15) * 128 +
                                          ((ks * 64 + g * 16) ^ ((ln15 & 7) << 4)));
            #pragma unroll
            for (int nq = 0; nq < 4; nq++)
                bf[nq] = *(const bf16x8*)(Bs + (wn * 64 + nq * 16 + ln15) * 128 +
                                          ((ks * 64 + g * 16) ^ ((ln15 & 7) << 4)));
            #pragma unroll
            for (int mq = 0; mq < 4; mq++)
                #pragma unroll
                for (int nq = 0; nq < 4; nq++)
                    acc[mq][nq] = mfma16(af[mq], bf[nq], acc[mq][nq]);
        }
        __syncthreads();
    }

    #pragma unroll
    for (int mq = 0; mq < 4; mq++) {
        #pragma unroll
        for (int nq = 0; nq < 4; nq++) {
            #pragma unroll
            for (int r = 0; r < 4; r++) {
                const int gr = row0 + wm * 64 + mq * 16 + g * 4 + r;
                const int gc = col0 + wn * 64 + nq * 16 + ln15;
                Cb[(size_t)gr * 1024 + gc] = f2bf(acc[mq][nq][r]);
            }
        }
    }
}

// ---------------------------------------------------------------------------
// Kernel 7: flash attention v8 (measured best). Grid (16,16): one 1024-thread
// block per CU, 128 q-rows x both batches. Per j-tile the CU stages ONCE:
// K/V (32 KB, global_load_lds, swizzled src) and the bias tile (32 KB f32,
// coalesced loads -> regs -> padded LDS [128][68]), both DOUBLE-buffered.
// Waves (b2 = w&1, wq = w>>1) compute independently between barriers.
__global__ void __launch_bounds__(1024, 4) attn_v8(
        const unsigned short* __restrict__ qb, const unsigned short* __restrict__ Kb,
        const unsigned short* __restrict__ Vt, const float* __restrict__ bias,
        const float* __restrict__ maskf, unsigned short* __restrict__ aout) {
    __shared__ __align__(16) unsigned char smem[135168];   // 64K kv dbuf + 68K bias dbuf
    const int t = threadIdx.x;
    const int w = t >> 6, lane = t & 63;
    const int g = lane >> 4, ln15 = lane & 15;
    const int i0 = blockIdx.x * 128, h = blockIdx.y;
    const int b2 = w & 1, wq = w >> 1;            // wave: batch b2, q-rows i0+wq*16..+15
    const int ls = lane >> 3;
    const int swz = (lane & 7) ^ ls;

    auto stage = [&](int jt, int cur) {
        const int j0 = jt * 64;
        const int quarter = w & 3;
        if (w < 8) {
            const int kb = (w >> 2) & 1;
            const unsigned short* src = Kb + (size_t)(kb * Jp + j0 + quarter * 16 + ls) * 64 + swz * 8;
            unsigned char* dst = smem + cur * 32768 + kb * 8192 + quarter * 2048;
            load_lds16(src, dst);
            load_lds16(src + (size_t)8 * 64, dst + 1024);
        } else {
            const int vb = (w >> 2) & 1;
            const unsigned short* src = Vt + (size_t)(vb * 64 + quarter * 16 + ls) * Jp + j0 + swz * 8;
            unsigned char* dst = smem + cur * 32768 + 16384 + vb * 8192 + quarter * 2048;
            load_lds16(src, dst);
            load_lds16(src + (size_t)8 * Jp, dst + 1024);
        }
    };

    const int bq  = t >> 3;          // 0..127: q-row this thread stages
    const int bs0 = t & 7;           // 16B slot (pass 0); pass 1 = +8
    const float* biasQrow = bias + ((size_t)h * N + i0 + bq) * J;
    auto bias_issue = [&](int jt, f32x4& r0, f32x4& r1) {
        const int j0 = jt * 64;
        if (j0 + 64 <= J) {
            r0 = loadu4(biasQrow + j0 + bs0 * 4);
            r1 = loadu4(biasQrow + j0 + (bs0 + 8) * 4);
        } else {
            #pragma unroll
            for (int c = 0; c < 4; c++) {
                const int jA = j0 + bs0 * 4 + c;
                const int jB = j0 + (bs0 + 8) * 4 + c;
                r0[c] = (jA < J) ? biasQrow[jA] : 0.f;
                r1[c] = (jB < J) ? biasQrow[jB] : 0.f;
            }
        }
    };
    auto bias_write = [&](int cur, const f32x4& r0, const f32x4& r1) {
        float* basep = (float*)(smem + 65536 + cur * 34816) + bq * 68;
        *(f32x4*)(basep + bs0 * 4) = r0;
        *(f32x4*)(basep + (bs0 + 8) * 4) = r1;
    };

    bf16x8 qf[2];
    #pragma unroll
    for (int ks = 0; ks < 2; ks++)
        qf[ks] = *(const bf16x8*)(qb + (size_t)(b2 * N + i0 + wq * 16 + ln15) * 1024 +
                                  h * 64 + ks * 32 + g * 8);

    float mrun = -1e30f, lrun = 0.f;
    f32x4 outA[4];
    #pragma unroll
    for (int nq = 0; nq < 4; nq++) outA[nq] = (f32x4){0.f, 0.f, 0.f, 0.f};

    const int srclA = ln15 + (((2 * g + 0) & 3) << 4);
    const int srclB = ln15 + (((2 * g + 1) & 3) << 4);

    auto compute = [&](int jt, int cur) {
        const int j0 = jt * 64;
        const unsigned char* Kl = smem + cur * 32768 + b2 * 8192;
        const unsigned char* Vl = smem + cur * 32768 + 16384 + b2 * 8192;
        const float* bb = (const float*)(smem + 65536 + cur * 34816) + (wq * 16 + ln15) * 68;

        f32x4 mk[4];
        #pragma unroll
        for (int jqm = 0; jqm < 4; jqm++)
            mk[jqm] = *(const f32x4*)(maskf + b2 * Jp + j0 + jqm * 16 + g * 4);
        f32x4 br[4];
        #pragma unroll
        for (int jqm = 0; jqm < 4; jqm++)
            br[jqm] = *(const f32x4*)(bb + (jqm * 4 + g) * 4);

        // S^T = K . Q : frag jqm rows j = j0+jqm*16+g*4+r, col q = ln15
        f32x4 S[4];
        #pragma unroll
        for (int jqm = 0; jqm < 4; jqm++) S[jqm] = (f32x4){0.f, 0.f, 0.f, 0.f};
        #pragma unroll
        for (int ks = 0; ks < 2; ks++) {
            bf16x8 ka[4];
            #pragma unroll
            for (int jqm = 0; jqm < 4; jqm++)
                ka[jqm] = *(const bf16x8*)(Kl + (jqm * 16 + ln15) * 128 +
                                           ((ks * 64 + g * 16) ^ ((ln15 & 7) << 4)));
            __builtin_amdgcn_s_setprio(1);
            #pragma unroll
            for (int jqm = 0; jqm < 4; jqm++)
                S[jqm] = mfma16(ka[jqm], qf[ks], S[jqm]);
            __builtin_amdgcn_s_setprio(0);
        }

        // log2 domain: S pre-scaled by log2e (via Wq), bias*log2e via fma
        float sv[4][4];
        #pragma unroll
        for (int jqm = 0; jqm < 4; jqm++)
            #pragma unroll
            for (int r = 0; r < 4; r++)
                sv[jqm][r] = fmaf(br[jqm][r], LOG2E, S[jqm][r]) + mk[jqm][r];

        float tmj[4];
        #pragma unroll
        for (int jqm = 0; jqm < 4; jqm++)
            tmj[jqm] = fmaxf(fmaxf(sv[jqm][0], sv[jqm][1]), fmaxf(sv[jqm][2], sv[jqm][3]));
        float tm = fmaxf(fmaxf(tmj[0], tmj[1]), fmaxf(tmj[2], tmj[3]));
        tm = fmaxf(tm, __shfl_xor(tm, 16));
        tm = fmaxf(tm, __shfl_xor(tm, 32));

        if (!__all(tm <= mrun)) {      // exact skip: rescale only if max grew
            const float mnew = fmaxf(mrun, tm);
            const float cor = fexp2(mrun - mnew);
            mrun = mnew;
            float corr[4];
            #pragma unroll
            for (int r = 0; r < 4; r++) corr[r] = __shfl(cor, g * 4 + r, 64);
            #pragma unroll
            for (int nq = 0; nq < 4; nq++)
                #pragma unroll
                for (int r = 0; r < 4; r++)
                    outA[nq][r] *= corr[r];
            lrun *= cor;
        }
        const float mcur = mrun;

        float p[4][4];
        #pragma unroll
        for (int jqm = 0; jqm < 4; jqm++)
            #pragma unroll
            for (int r = 0; r < 4; r++)
                p[jqm][r] = fexp2(sv[jqm][r] - mcur);
        float tsj[4];
        #pragma unroll
        for (int jqm = 0; jqm < 4; jqm++)
            tsj[jqm] = (p[jqm][0] + p[jqm][1]) + (p[jqm][2] + p[jqm][3]);
        float ts = (tsj[0] + tsj[1]) + (tsj[2] + tsj[3]);
        ts += __shfl_xor(ts, 16);
        ts += __shfl_xor(ts, 32);
        lrun += ts;

        unsigned int Wp[4][2];
        #pragma unroll
        for (int jqm = 0; jqm < 4; jqm++) {
            Wp[jqm][0] = packbf2(p[jqm][0], p[jqm][1]);
            Wp[jqm][1] = packbf2(p[jqm][2], p[jqm][3]);
        }

        // repack to PV A-fragments: lane needs P[q=ln15][j=ks*32+g*8+0..7]
        #pragma unroll
        for (int ks = 0; ks < 2; ks++) {
            uint4v wd;
            #pragma unroll
            for (int widx = 0; widx < 4; widx++) {
                const int srcl = (widx >> 1) ? srclB : srclA;
                const int t0 = __shfl((int)Wp[ks * 2 + 0][widx & 1], srcl, 64);
                const int t1 = __shfl((int)Wp[ks * 2 + 1][widx & 1], srcl, 64);
                wd[widx] = (unsigned int)((g >> 1) ? t1 : t0);
            }
            const bf16x8 pa = __builtin_bit_cast(bf16x8, wd);
            bf16x8 vf[4];
            #pragma unroll
            for (int nq = 0; nq < 4; nq++)
                vf[nq] = *(const bf16x8*)(Vl + (nq * 16 + ln15) * 128 +
                                          ((ks * 64 + g * 16) ^ ((ln15 & 7) << 4)));
            __builtin_amdgcn_s_setprio(1);
            #pragma unroll
            for (int nq = 0; nq < 4; nq++)
                outA[nq] = mfma16(pa, vf[nq], outA[nq]);
            __builtin_amdgcn_s_setprio(0);
        }
    };

    // ---- pipeline: bias regs in flight during compute; all LDS dbuf'd.
    f32x4 bR0, bR1;
    bias_issue(0, bR0, bR1);
    stage(0, 0);
    bias_write(0, bR0, bR1);       // compiler inserts counted vmcnt wait for bR
    __syncthreads();
    for (int jt = 0; jt < NT; jt++) {
        const int cur = jt & 1;
        if (jt + 1 < NT) {
            bias_issue(jt + 1, bR0, bR1);   // HBM latency hides under compute
            stage(jt + 1, cur ^ 1);
        }
        compute(jt, cur);
        if (jt + 1 < NT) bias_write(cur ^ 1, bR0, bR1);
        __syncthreads();
    }

    const float inv = 1.0f / lrun;
    float invr[4];
    #pragma unroll
    for (int r = 0; r < 4; r++) invr[r] = __shfl(inv, g * 4 + r, 64);
    #pragma unroll
    for (int nq = 0; nq < 4; nq++)
        #pragma unroll
        for (int r = 0; r < 4; r++)
            aout[(size_t)(b2 * N + i0 + wq * 16 + g * 4 + r) * 1024 +
                 h * 64 + nq * 16 + ln15] = f2bf(outA[nq][r] * invr[r]);
}

// ---------------------------------------------------------------------------
extern "C" void kernel_launch(void* const* d_in, const int* in_sizes, int n_in,
                              void* d_out, int out_size, void* d_ws, size_t ws_size,
                              hipStream_t stream) {
    const float* x         = (const float*)d_in[0];
    const float* context   = (const float*)d_in[1];
    const void*  mask      = d_in[2];
    const float* bias      = (const float*)d_in[3];
    const float* norm_g    = (const float*)d_in[4];
    const float* null_kv   = (const float*)d_in[5];
    const float* Wq        = (const float*)d_in[6];
    const float* Wkv       = (const float*)d_in[7];
    const float* ctx_ln_w  = (const float*)d_in[8];
    const float* ctx_ln_b  = (const float*)d_in[9];
    const float* Wctx      = (const float*)d_in[10];
    const float* bctx      = (const float*)d_in[11];
    const float* Wout      = (const float*)d_in[12];
    const float* out_gamma = (const float*)d_in[13];
    float* out = (float*)d_out;

    unsigned char* wsb = (unsigned char*)d_ws;
    unsigned short* xnb   = (unsigned short*)(wsb + 0);          //  8 MB bf16
    unsigned short* qbb   = (unsigned short*)(wsb + 8388608);    //  8 MB bf16
    unsigned short* yb    = qbb;                                 //  8 MB bf16 (qbb dead after attn)
    unsigned short* aoutp = (unsigned short*)(wsb + 16777216);   //  8 MB bf16
    unsigned short* KbP   = (unsigned short*)(wsb + 25165824);   // 2*Jp*64 bf16
    unsigned short* VtP   = (unsigned short*)(wsb + 25772032);   // 2*64*Jp bf16
    float*          maskf = (float*)(wsb + 26378240);            // 2*Jp f32
    unsigned short* WqT   = (unsigned short*)(wsb + 26397184);   // 2 MB
    unsigned short* WkvT  = (unsigned short*)(wsb + 28494336);   // 256 KB
    unsigned short* WoutT = (unsigned short*)(wsb + 28756480);   // 2 MB

    // setup: weight transposes + mask + pads + null token (one launch)
    setup_all<<<547, 256, 0, stream>>>(Wq, Wkv, Wout, WqT, WkvT, WoutT,
                                       mask, maskf, KbP, VtP, null_kv);
    ln1024<0, 1><<<B * N, 256, 0, stream>>>(x, norm_g, xnb);
    ctx_proj<<<B * C, 128, 0, stream>>>(context, ctx_ln_w, ctx_ln_b, Wctx, bctx, KbP, VtP);
    // merged q + kv projections: q = LN(x)@(Wq*scale), kv = LN(x)@Wkv
    proj_gemm<<<dim3(32, 9), 256, 0, stream>>>(xnb, WqT, WkvT, qbb, KbP, VtP);
    attn_v8<<<dim3(16, 16), 1024, 0, stream>>>(qbb, KbP, VtP, bias, maskf, aoutp);
    // y = attn_out @ Wout -> bf16 (overwrites qbb region; qbb consumed above)
    gemm_out<<<dim3(32, 8), 256, 0, stream>>>(aoutp, WoutT, yb);
    ln1024<1, 0><<<B * N, 256, 0, stream>>>(yb, out_gamma, out);
}